// Round 27
// baseline (207.765 us; speedup 1.0000x reference)
//
#include <hip/hip_runtime.h>
#include <math.h>

typedef __attribute__((ext_vector_type(8))) short bf16x8;
typedef __attribute__((ext_vector_type(8))) unsigned short u16x8;
typedef __attribute__((ext_vector_type(4))) unsigned short u16x4;
typedef __attribute__((ext_vector_type(4))) float f32x4;
typedef unsigned short u16;

// Shapes: b=2, T=15, Hn=256, D=128, P=64, PPP=4096, REC=3
// d_out layout (f32): x_e[983040] | x_h[983040] | x_p[31457280] | x_h_p[31457280]
#define XE_OFF   0
#define XH_OFF   983040
#define XP_OFF   1966080
#define XHP_OFF  33423360

// scratch (float offsets) inside x_h_p region — all dead before recover(xh->xhp)
#define SCR_COS   0         // 8192
#define SCR_SIN   8192      // 8192
#define SCR_Q     16384     // 65536  q[b][h][w]
#define SCR_K     81920     // 65536  k[b][g][w]
#define SCR_V     147456    // 983040 v[b][c][g][w]
#define SCR_HA    1130496   // 983040
#define SCR_HB    2113536   // 983040
#define SCR_M1    3096576   // 65536  m1[b][h][w]
#define SCR_S1    3162112   // 65536  S1[b][h][w]
#define SCR_AW    3227648   // 983040 accW[b][c][h][w]
#define SCR_VT    4210688   // 983040 vT[b][c][w][g]
#define SCR_KT    5193728   // 65536  kT[b][w][g]
#define SCR_QT    5259264   // 65536  qT[b][w][h]
#define SCR_OHT   5324800   // 983040 outHT[b][c][w][h]
#define SCR_M2    6307840   // 65536  m2T[b][w][h]
#define SCR_S2    6373376   // 65536  S2T[b][w][h]
#define SCR_PART  7487488   // 8 x 983040 u16 = 3932160 floats (ends 11419648 < 31457280)
// d_ws layout (bytes): Wp2t[0,1048576) Wembt[1048576,2097152)
//                      Wp1t[2097152,2129920) Wmlpt[2129920,2162688)

__device__ __forceinline__ u16 f2bf(float f) {
    unsigned u = __float_as_uint(f);
    return (u16)((u + 0x7fffu + ((u >> 16) & 1)) >> 16);
}
__device__ __forceinline__ float bf2f(u16 h) {
    return __uint_as_float(((unsigned)h) << 16);
}

union U8 { u16 h[8]; bf16x8 v; u16x8 u; };

// ---------- prep: rope tables + all 4 weight transpose/cvt in ONE launch ----------
__global__ __launch_bounds__(256) void prep_k(const float* __restrict__ Wemb,
                                              const float* __restrict__ Wp1,
                                              const float* __restrict__ Wmlp,
                                              const float* __restrict__ Wp2,
                                              float* __restrict__ cosb, float* __restrict__ sinb,
                                              u16* __restrict__ Wembt, u16* __restrict__ Wp1t,
                                              u16* __restrict__ Wmlpt, u16* __restrict__ Wp2t) {
    __shared__ float tl[32][33];
    int bid = blockIdx.x, tid = threadIdx.x;
    if (bid < 32) {
        int i = bid * 256 + tid;
        int n = i >> 5, j = i & 31;
        float inv = expf(-(float)j * 0.28782313662425573f);  // 10000^(-2j/64)
        float ang = (float)n * inv;
        cosb[i] = cosf(ang);
        sinb[i] = sinf(ang);
        return;
    }
    const float* in; u16* outp; int K, N, gx, gy;
    if (bid < 544)      { int i = bid - 32;  in = Wemb; outp = Wembt; K = 4096; N = 128;  gx = i & 3;   gy = i >> 2; }
    else if (bid < 560) { int i = bid - 544; in = Wp1;  outp = Wp1t;  K = 128;  N = 128;  gx = i & 3;   gy = i >> 2; }
    else if (bid < 576) { int i = bid - 560; in = Wmlp; outp = Wmlpt; K = 128;  N = 128;  gx = i & 3;   gy = i >> 2; }
    else                { int i = bid - 576; in = Wp2;  outp = Wp2t;  K = 128;  N = 4096; gx = i & 127; gy = i >> 7; }
    int n0 = gx * 32, k0 = gy * 32;
    int tx = tid & 31, ty = tid >> 5;
#pragma unroll
    for (int r = 0; r < 4; ++r)
        tl[ty + r * 8][tx] = in[(size_t)(k0 + ty + r * 8) * N + n0 + tx];
    __syncthreads();
#pragma unroll
    for (int r = 0; r < 4; ++r)
        outp[(size_t)(n0 + ty + r * 8) * K + k0 + tx] = f2bf(tl[tx][ty + r * 8]);
}

// ---------- embed: MFMA bf16, split-K x8, coalesced A staging + depth-2 prefetch ----------
// partials stored as bf16 (halves partial round-trip traffic)
__global__ __launch_bounds__(256) void embed_mfma_k(const float* __restrict__ x,
                                                    const u16* __restrict__ Wembt,
                                                    u16* __restrict__ part) {
    __shared__ char Al[64 * 128];
    __shared__ char Bl[128 * 128];
    int ck = blockIdx.x, mt = blockIdx.y;
    int m0 = mt * 64;
    int bt = m0 >> 8;
    int n0r = m0 & 255;
    const float* xb = x + (size_t)bt * 1048576;
    int tid = threadIdx.x;
    int ln = tid & 63, wv = tid >> 6;
    int wm = wv >> 1, wn = wv & 1;

    f32x4 acc[2][4];
#pragma unroll
    for (int mi = 0; mi < 2; ++mi)
#pragma unroll
        for (int ni = 0; ni < 4; ++ni) acc[mi][ni] = (f32x4){0.f, 0.f, 0.f, 0.f};

    // coalesced A staging: wave wv covers n-group (n0r>>4)+wv; lane ln covers
    // floats ln*16..ln*16+15 of the 1024-float (group,py) line.
    int ar = wv * 16 + (ln >> 2);
    int aseg = ln & 3;
    const float* abase = xb + ((size_t)((n0r >> 4) + wv)) * 65536 + ln * 16;
    // B staging coords: 4 chunks per thread
    int bn[4], bk0[4];
#pragma unroll
    for (int j = 0; j < 4; ++j) {
        int c = tid + 256 * j;
        bn[j] = c >> 3; bk0[j] = (c & 7) * 8;
    }

    // depth-2 prefetch buffers: preload phases 0 and 1
    f32x4 af[2][4];
    U8 bfr[2][4];
#pragma unroll
    for (int p = 0; p < 2; ++p) {
        const float* src = abase + (size_t)(ck * 8 + p) * 1024;
#pragma unroll
        for (int j = 0; j < 4; ++j) af[p][j] = ((const f32x4*)src)[j];
        int kb = ck * 512 + p * 64;
#pragma unroll
        for (int j = 0; j < 4; ++j)
            bfr[p][j].u = *(const u16x8*)(Wembt + (size_t)bn[j] * 4096 + kb + bk0[j]);
    }

#pragma unroll
    for (int bk = 0; bk < 8; ++bk) {
        const int cur = bk & 1;           // compile-time after full unroll
        __syncthreads();   // prior MFMA LDS reads complete
        {
            U8 u0, u1;
            u0.h[0] = f2bf(af[cur][0].x); u0.h[1] = f2bf(af[cur][0].y); u0.h[2] = f2bf(af[cur][0].z); u0.h[3] = f2bf(af[cur][0].w);
            u0.h[4] = f2bf(af[cur][1].x); u0.h[5] = f2bf(af[cur][1].y); u0.h[6] = f2bf(af[cur][1].z); u0.h[7] = f2bf(af[cur][1].w);
            u1.h[0] = f2bf(af[cur][2].x); u1.h[1] = f2bf(af[cur][2].y); u1.h[2] = f2bf(af[cur][2].z); u1.h[3] = f2bf(af[cur][2].w);
            u1.h[4] = f2bf(af[cur][3].x); u1.h[5] = f2bf(af[cur][3].y); u1.h[6] = f2bf(af[cur][3].z); u1.h[7] = f2bf(af[cur][3].w);
            int sw = (ar & 7) << 4;
            *(bf16x8*)(Al + ar * 128 + ((aseg * 32) ^ sw))      = u0.v;
            *(bf16x8*)(Al + ar * 128 + ((aseg * 32 + 16) ^ sw)) = u1.v;
#pragma unroll
            for (int j = 0; j < 4; ++j)
                *(bf16x8*)(Bl + bn[j] * 128 + ((bk0[j] * 2) ^ ((bn[j] & 7) << 4))) = bfr[cur][j].v;
        }
        __syncthreads();   // staging visible
        if (bk < 6) {      // prefetch phase bk+2 into the just-freed buffer
            const float* src = abase + (size_t)(ck * 8 + bk + 2) * 1024;
#pragma unroll
            for (int j = 0; j < 4; ++j) af[cur][j] = ((const f32x4*)src)[j];
            int kb = ck * 512 + (bk + 2) * 64;
#pragma unroll
            for (int j = 0; j < 4; ++j)
                bfr[cur][j].u = *(const u16x8*)(Wembt + (size_t)bn[j] * 4096 + kb + bk0[j]);
        }
#pragma unroll
        for (int ks = 0; ks < 2; ++ks) {
            int k2 = (ks * 32 + (ln >> 4) * 8) * 2;
            bf16x8 a[2], b[4];
#pragma unroll
            for (int mi = 0; mi < 2; ++mi) {
                int row = wm * 32 + mi * 16 + (ln & 15);
                a[mi] = *(const bf16x8*)(Al + row * 128 + (k2 ^ ((row & 7) << 4)));
            }
#pragma unroll
            for (int ni = 0; ni < 4; ++ni) {
                int n = wn * 64 + ni * 16 + (ln & 15);
                b[ni] = *(const bf16x8*)(Bl + n * 128 + (k2 ^ ((n & 7) << 4)));
            }
#pragma unroll
            for (int mi = 0; mi < 2; ++mi)
#pragma unroll
                for (int ni = 0; ni < 4; ++ni)
                    acc[mi][ni] = __builtin_amdgcn_mfma_f32_16x16x32_bf16(a[mi], b[ni], acc[mi][ni], 0, 0, 0);
        }
    }
    u16* p = part + (size_t)ck * 983040;
#pragma unroll
    for (int mi = 0; mi < 2; ++mi)
#pragma unroll
        for (int ni = 0; ni < 4; ++ni)
#pragma unroll
            for (int r = 0; r < 4; ++r) {
                int row = m0 + wm * 32 + mi * 16 + (ln >> 4) * 4 + r;
                int col = wn * 64 + ni * 16 + (ln & 15);
                p[(size_t)row * 128 + col] = f2bf(acc[mi][ni][r]);
            }
}

// xe = sum of 8 bf16 partials + bias. grid 480; 8 floats/thread.
__global__ __launch_bounds__(256) void embed_reduce_k(const u16* __restrict__ part,
                                                      const float* __restrict__ bemb,
                                                      float* __restrict__ xe) {
    int i = blockIdx.x * 256 + threadIdx.x;    // 122880 total, 8 floats each
    float s[8];
#pragma unroll
    for (int e = 0; e < 8; ++e) s[e] = 0.f;
#pragma unroll
    for (int j = 0; j < 8; ++j) {
        U8 h; h.u = *(const u16x8*)(part + (size_t)j * 983040 + (size_t)i * 8);
#pragma unroll
        for (int e = 0; e < 8; ++e) s[e] += bf2f(h.h[e]);
    }
    int col0 = (i & 15) * 8;
#pragma unroll
    for (int e = 0; e < 8; ++e) s[e] += bemb[col0 + e];
    float4 o0 = {s[0], s[1], s[2], s[3]};
    float4 o1 = {s[4], s[5], s[6], s[7]};
    ((float4*)(xe + (size_t)i * 8))[0] = o0;
    ((float4*)(xe + (size_t)i * 8))[1] = o1;
}

// ---------- generic K=128 MFMA GEMM (used only for xh = h @ Wmlp) ----------
template<int ABF, int OBF, int HASB>
__global__ __launch_bounds__(256) void gemm_bt_k(const void* __restrict__ Ap,
                                                 const u16* __restrict__ Bt,
                                                 const float* __restrict__ bias,
                                                 void* __restrict__ outp, int N) {
    __shared__ char Al[64 * 256];
    __shared__ char Bl[128 * 256];
    int n0 = blockIdx.x * 128, m0 = blockIdx.y * 64;
    int tid = threadIdx.x;
    int ln = tid & 63, wv = tid >> 6;
    int wm = wv >> 1, wn = wv & 1;
    {
        int row = tid >> 2, kseg = (tid & 3) * 32;
        int sw = (row & 7) << 4;
        if (ABF) {
            const u16* src = (const u16*)Ap + (size_t)(m0 + row) * 128 + kseg;
#pragma unroll
            for (int j = 0; j < 4; ++j) {
                U8 u; u.u = *(const u16x8*)(src + j * 8);
                *(bf16x8*)(Al + row * 256 + (((kseg + j * 8) * 2) ^ sw)) = u.v;
            }
        } else {
            const float* src = (const float*)Ap + (size_t)(m0 + row) * 128 + kseg;
#pragma unroll
            for (int j = 0; j < 4; ++j) {
                float4 f0 = ((const float4*)src)[2 * j];
                float4 f1 = ((const float4*)src)[2 * j + 1];
                U8 u;
                u.h[0] = f2bf(f0.x); u.h[1] = f2bf(f0.y); u.h[2] = f2bf(f0.z); u.h[3] = f2bf(f0.w);
                u.h[4] = f2bf(f1.x); u.h[5] = f2bf(f1.y); u.h[6] = f2bf(f1.z); u.h[7] = f2bf(f1.w);
                *(bf16x8*)(Al + row * 256 + (((kseg + j * 8) * 2) ^ sw)) = u.v;
            }
        }
    }
    {
        int n = tid >> 1, kseg = (tid & 1) * 64;
        int sw = (n & 7) << 4;
        const u16* src = Bt + (size_t)(n0 + n) * 128 + kseg;
#pragma unroll
        for (int j = 0; j < 8; ++j) {
            U8 u; u.u = *(const u16x8*)(src + j * 8);
            *(bf16x8*)(Bl + n * 256 + (((kseg + j * 8) * 2) ^ sw)) = u.v;
        }
    }
    __syncthreads();
    f32x4 acc[2][4];
#pragma unroll
    for (int mi = 0; mi < 2; ++mi)
#pragma unroll
        for (int ni = 0; ni < 4; ++ni) acc[mi][ni] = (f32x4){0.f, 0.f, 0.f, 0.f};
#pragma unroll
    for (int ks = 0; ks < 4; ++ks) {
        int k2 = (ks * 32 + (ln >> 4) * 8) * 2;
        bf16x8 a[2], b[4];
#pragma unroll
        for (int mi = 0; mi < 2; ++mi) {
            int row = wm * 32 + mi * 16 + (ln & 15);
            a[mi] = *(const bf16x8*)(Al + row * 256 + (k2 ^ ((row & 7) << 4)));
        }
#pragma unroll
        for (int ni = 0; ni < 4; ++ni) {
            int n = wn * 64 + ni * 16 + (ln & 15);
            b[ni] = *(const bf16x8*)(Bl + n * 256 + (k2 ^ ((n & 7) << 4)));
        }
#pragma unroll
        for (int mi = 0; mi < 2; ++mi)
#pragma unroll
            for (int ni = 0; ni < 4; ++ni)
                acc[mi][ni] = __builtin_amdgcn_mfma_f32_16x16x32_bf16(a[mi], b[ni], acc[mi][ni], 0, 0, 0);
    }
#pragma unroll
    for (int mi = 0; mi < 2; ++mi)
#pragma unroll
        for (int ni = 0; ni < 4; ++ni)
#pragma unroll
            for (int r = 0; r < 4; ++r) {
                int row = m0 + wm * 32 + mi * 16 + (ln >> 4) * 4 + r;
                int col = n0 + wn * 64 + ni * 16 + (ln & 15);
                float v = acc[mi][ni][r];
                if (HASB) v += bias[col];
                if (OBF) ((u16*)outp)[(size_t)row * N + col] = f2bf(v);
                else     ((float*)outp)[(size_t)row * N + col] = v;
            }
}

// ---------- fused recover x2: both xe->xp and xh->xhp in ONE launch ----------
// grid (8, 240): blockIdx.y < 120 -> xe->xp, else xh->xhp.
__global__ __launch_bounds__(256) void recover2_k(const float* __restrict__ A0,
                                                  const float* __restrict__ A1,
                                                  const u16* __restrict__ Wp1t,
                                                  const float* __restrict__ bp1,
                                                  const u16* __restrict__ Wp2t,
                                                  const float* __restrict__ bp2,
                                                  float* __restrict__ out0,
                                                  float* __restrict__ out1) {
    __shared__ char Zl[64 * 256];    // z bf16
    __shared__ char Bl[64 * 256];    // weight chunk: 64 n-rows x 128 k bf16
    __shared__ char Al2[64 * 256];   // A bf16
    __shared__ float Ol[64][65];     // output chunk staging (dedicated)
    int sel = blockIdx.y >= 120;
    const float* A = sel ? A1 : A0;
    float* outp = sel ? out1 : out0;
    int cb = blockIdx.x * 512, m0 = (blockIdx.y - (sel ? 120 : 0)) * 64;
    int tid = threadIdx.x, ln = tid & 63, wv = tid >> 6;
    int wm = wv >> 1, wn = wv & 1;

    // stage A (f32 -> bf16) into Al2
    {
        int row = tid >> 2, kseg = (tid & 3) * 32;
        int sw = (row & 7) << 4;
        const float* src = A + (size_t)(m0 + row) * 128 + kseg;
#pragma unroll
        for (int j = 0; j < 4; ++j) {
            float4 f0 = ((const float4*)src)[2 * j];
            float4 f1 = ((const float4*)src)[2 * j + 1];
            U8 u;
            u.h[0] = f2bf(f0.x); u.h[1] = f2bf(f0.y); u.h[2] = f2bf(f0.z); u.h[3] = f2bf(f0.w);
            u.h[4] = f2bf(f1.x); u.h[5] = f2bf(f1.y); u.h[6] = f2bf(f1.z); u.h[7] = f2bf(f1.w);
            *(bf16x8*)(Al2 + row * 256 + (((kseg + j * 8) * 2) ^ sw)) = u.v;
        }
    }
    // phase 1: z = A @ Wp1 (+bp1) in 2 chunks of 64 cols
    f32x4 zacc[2][4];
#pragma unroll
    for (int mi = 0; mi < 2; ++mi)
#pragma unroll
        for (int ni = 0; ni < 4; ++ni) zacc[mi][ni] = (f32x4){0.f, 0.f, 0.f, 0.f};
    for (int nc = 0; nc < 2; ++nc) {
        __syncthreads();
        {
            int n = tid >> 2, ks2 = (tid & 3) * 32;
            int swb = (n & 7) << 4;
            const u16* bsrc = Wp1t + (size_t)(nc * 64 + n) * 128 + ks2;
#pragma unroll
            for (int j = 0; j < 4; ++j) {
                U8 u; u.u = *(const u16x8*)(bsrc + j * 8);
                *(bf16x8*)(Bl + n * 256 + (((ks2 + j * 8) * 2) ^ swb)) = u.v;
            }
        }
        __syncthreads();
#pragma unroll
        for (int ks = 0; ks < 4; ++ks) {
            int k2 = (ks * 32 + (ln >> 4) * 8) * 2;
            bf16x8 a[2], b[2];
#pragma unroll
            for (int mi = 0; mi < 2; ++mi) {
                int row = wm * 32 + mi * 16 + (ln & 15);
                a[mi] = *(const bf16x8*)(Al2 + row * 256 + (k2 ^ ((row & 7) << 4)));
            }
#pragma unroll
            for (int ni = 0; ni < 2; ++ni) {
                int n = wn * 32 + ni * 16 + (ln & 15);
                b[ni] = *(const bf16x8*)(Bl + n * 256 + (k2 ^ ((n & 7) << 4)));
            }
#pragma unroll
            for (int mi = 0; mi < 2; ++mi)
#pragma unroll
                for (int ni = 0; ni < 2; ++ni)
                    zacc[mi][nc * 2 + ni] = __builtin_amdgcn_mfma_f32_16x16x32_bf16(a[mi], b[ni], zacc[mi][nc * 2 + ni], 0, 0, 0);
        }
    }
    // write z (bf16) into Zl; visible before first phase-2 read via nb-loop barrier
#pragma unroll
    for (int ni4 = 0; ni4 < 4; ++ni4) {
        int col = (ni4 >> 1) * 64 + wn * 32 + (ni4 & 1) * 16 + (ln & 15);
        float bb = bp1[col];
#pragma unroll
        for (int mi = 0; mi < 2; ++mi)
#pragma unroll
            for (int r = 0; r < 4; ++r) {
                int row = wm * 32 + mi * 16 + (ln >> 4) * 4 + r;
                *(u16*)(Zl + row * 256 + ((col * 2) ^ ((row & 7) << 4))) =
                    f2bf(zacc[mi][ni4][r] + bb);
            }
    }
    // phase 2: out slice in 8 chunks of 64 cols; coalesced write via Ol
    for (int nb = 0; nb < 8; ++nb) {
        __syncthreads();   // z/Ol reads of prev iteration done; Bl reads done
        {
            int n = tid >> 2, ks2 = (tid & 3) * 32;
            int swb = (n & 7) << 4;
            const u16* bsrc = Wp2t + (size_t)(cb + nb * 64 + n) * 128 + ks2;
#pragma unroll
            for (int j = 0; j < 4; ++j) {
                U8 u; u.u = *(const u16x8*)(bsrc + j * 8);
                *(bf16x8*)(Bl + n * 256 + (((ks2 + j * 8) * 2) ^ swb)) = u.v;
            }
        }
        __syncthreads();
        f32x4 acc[2][2];
#pragma unroll
        for (int mi = 0; mi < 2; ++mi)
#pragma unroll
            for (int ni = 0; ni < 2; ++ni) acc[mi][ni] = (f32x4){0.f, 0.f, 0.f, 0.f};
#pragma unroll
        for (int ks = 0; ks < 4; ++ks) {
            int k2 = (ks * 32 + (ln >> 4) * 8) * 2;
            bf16x8 a[2], b[2];
#pragma unroll
            for (int mi = 0; mi < 2; ++mi) {
                int row = wm * 32 + mi * 16 + (ln & 15);
                a[mi] = *(const bf16x8*)(Zl + row * 256 + (k2 ^ ((row & 7) << 4)));
            }
#pragma unroll
            for (int ni = 0; ni < 2; ++ni) {
                int n = wn * 32 + ni * 16 + (ln & 15);
                b[ni] = *(const bf16x8*)(Bl + n * 256 + (k2 ^ ((n & 7) << 4)));
            }
#pragma unroll
            for (int mi = 0; mi < 2; ++mi)
#pragma unroll
                for (int ni = 0; ni < 2; ++ni)
                    acc[mi][ni] = __builtin_amdgcn_mfma_f32_16x16x32_bf16(a[mi], b[ni], acc[mi][ni], 0, 0, 0);
        }
        // stage fragments into Ol [row][col] (bias added here)
#pragma unroll
        for (int ni = 0; ni < 2; ++ni) {
            int coll = wn * 32 + ni * 16 + (ln & 15);
            float bb = bp2[cb + nb * 64 + coll];
#pragma unroll
            for (int mi = 0; mi < 2; ++mi)
#pragma unroll
                for (int r = 0; r < 4; ++r) {
                    int rowl = wm * 32 + mi * 16 + (ln >> 4) * 4 + r;
                    Ol[rowl][coll] = acc[mi][ni][r] + bb;
                }
        }
        __syncthreads();   // Ol visible
        // coalesced write: 16 threads per row -> 256B contiguous per row
#pragma unroll
        for (int j = 0; j < 4; ++j) {
            int e = tid + 256 * j;           // 1024 float4s
            int rowl = e >> 4, c4 = e & 15;
            float4 o;
            o.x = Ol[rowl][c4 * 4 + 0];
            o.y = Ol[rowl][c4 * 4 + 1];
            o.z = Ol[rowl][c4 * 4 + 2];
            o.w = Ol[rowl][c4 * 4 + 3];
            float* dst = outp + (size_t)(m0 + rowl) * 4096 + cb + nb * 64 + c4 * 4;
            __builtin_nontemporal_store(o.x, dst + 0);
            __builtin_nontemporal_store(o.y, dst + 1);
            __builtin_nontemporal_store(o.z, dst + 2);
            __builtin_nontemporal_store(o.w, dst + 3);
        }
    }
}

// ---------- attention 1: qkv + W-part, 256 threads (2 halves), coalesced I/O ----------
__global__ __launch_bounds__(256) void qkvW_k(const float* __restrict__ hin,
    const float* __restrict__ Wq, const float* __restrict__ bq,
    const float* __restrict__ Wk, const float* __restrict__ bk,
    const float* __restrict__ Wv, const float* __restrict__ bv,
    const float* __restrict__ cosb, const float* __restrict__ sinb,
    float* __restrict__ q, float* __restrict__ k, float* __restrict__ v,
    float* __restrict__ m1g, float* __restrict__ S1g, float* __restrict__ accW) {
    __shared__ char Pl[128 * 256];
    __shared__ char Vt[16 * 256];
    __shared__ float klds[128];
    __shared__ float qlds[128];
    __shared__ float red[2];
    __shared__ float ol[128][17];
    int b = blockIdx.x >> 8, hh = blockIdx.x & 255;
    int tid = threadIdx.x;
    int d = tid & 127, half = tid >> 7;

    if (half == 0) {
        float hv[15];
#pragma unroll
        for (int t = 0; t < 15; ++t)
            hv[t] = hin[(((size_t)b * 15 + t) * 256 + hh) * 128 + d];
        float qp = bq[0], kp = bk[0];
#pragma unroll
        for (int t = 0; t < 15; ++t) {
            qp = fmaf(hv[t], Wq[t], qp);
            kp = fmaf(hv[t], Wk[t], kp);
        }
        float qpart = __shfl_xor(qp, 1);
        float kpart = __shfl_xor(kp, 1);
        float qo = qp, ko = kp;
        if (d < 64) {
            int j = d >> 1;
            float c = cosb[hh * 32 + j], s = sinb[hh * 32 + j];
            if (d & 1) { qo = fmaf(qp, c,  qpart * s); ko = fmaf(kp, c,  kpart * s); }
            else       { qo = fmaf(qp, c, -qpart * s); ko = fmaf(kp, c, -kpart * s); }
        }
        q[((size_t)b * 256 + hh) * 128 + d] = qo;
        k[((size_t)b * 256 + hh) * 128 + d] = ko;
        klds[d] = ko;
        qlds[d] = qo;
        float ka = fabsf(ko);
#pragma unroll
        for (int off = 32; off >= 1; off >>= 1) ka = fmaxf(ka, __shfl_xor(ka, off));
        if ((tid & 63) == 0) red[tid >> 6] = ka;
    } else {
        float hv[15];
#pragma unroll
        for (int t = 0; t < 15; ++t)
            hv[t] = hin[(((size_t)b * 15 + t) * 256 + hh) * 128 + d];
        float vv[15];
#pragma unroll
        for (int c = 0; c < 15; ++c) {
            float a = bv[c];
#pragma unroll
            for (int t = 0; t < 15; ++t) a = fmaf(hv[t], Wv[c * 15 + t], a);
            vv[c] = a;
        }
#pragma unroll
        for (int c = 0; c < 15; ++c)
            v[(((size_t)b * 15 + c) * 256 + hh) * 128 + d] = vv[c];
#pragma unroll
        for (int c = 0; c < 15; ++c)
            *(u16*)(Vt + ((c * 256 + d * 2) ^ ((c & 7) << 4))) = f2bf(vv[c]);
        *(u16*)(Vt + ((15 * 256 + d * 2) ^ 112)) = 0x3F80;
    }
    __syncthreads();
    float ka = fmaxf(red[0], red[1]);
    float qo = qlds[d];
    float m1 = fabsf(qo) * ka;
    if (half == 0) m1g[((size_t)b * 256 + hh) * 128 + d] = m1;
    int swp = (d & 7) << 4;
    int u0 = half * 64;
#pragma unroll 4
    for (int u8 = 0; u8 < 64; u8 += 8) {
        f32x4 k0 = *(const f32x4*)&klds[u0 + u8];
        f32x4 k1 = *(const f32x4*)&klds[u0 + u8 + 4];
        U8 u;
        u.h[0] = f2bf(__expf(fmaf(qo, k0.x, -m1)));
        u.h[1] = f2bf(__expf(fmaf(qo, k0.y, -m1)));
        u.h[2] = f2bf(__expf(fmaf(qo, k0.z, -m1)));
        u.h[3] = f2bf(__expf(fmaf(qo, k0.w, -m1)));
        u.h[4] = f2bf(__expf(fmaf(qo, k1.x, -m1)));
        u.h[5] = f2bf(__expf(fmaf(qo, k1.y, -m1)));
        u.h[6] = f2bf(__expf(fmaf(qo, k1.z, -m1)));
        u.h[7] = f2bf(__expf(fmaf(qo, k1.w, -m1)));
        *(bf16x8*)(Pl + d * 256 + (((u0 + u8) * 2) ^ swp)) = u.v;
    }
    __syncthreads();
    int ln = tid & 63, wvv = tid >> 6;
    f32x4 acc[2];
    acc[0] = (f32x4){0.f, 0.f, 0.f, 0.f};
    acc[1] = (f32x4){0.f, 0.f, 0.f, 0.f};
#pragma unroll
    for (int ks = 0; ks < 4; ++ks) {
        int k2 = (ks * 32 + (ln >> 4) * 8) * 2;
        int n = ln & 15;
        bf16x8 bf = *(const bf16x8*)(Vt + n * 256 + (k2 ^ ((n & 7) << 4)));
#pragma unroll
        for (int mt = 0; mt < 2; ++mt) {
            int row = wvv * 32 + mt * 16 + (ln & 15);
            bf16x8 a = *(const bf16x8*)(Pl + row * 256 + (k2 ^ ((row & 7) << 4)));
            acc[mt] = __builtin_amdgcn_mfma_f32_16x16x32_bf16(a, bf, acc[mt], 0, 0, 0);
        }
    }
    {
        int c = ln & 15;
#pragma unroll
        for (int mt = 0; mt < 2; ++mt)
#pragma unroll
            for (int r = 0; r < 4; ++r)
                ol[wvv * 32 + mt * 16 + (ln >> 4) * 4 + r][c] = acc[mt][r];
    }
    __syncthreads();
    if (half == 0) S1g[((size_t)b * 256 + hh) * 128 + d] = ol[d][15];
    for (int e = tid; e < 1920; e += 256) {
        int c = e >> 7, w = e & 127;
        accW[(((size_t)b * 15 + c) * 256 + hh) * 128 + w] = ol[w][c];
    }
}

// ---------- attention 2: tiled transposes v->vT, k->kT, q->qT ----------
__global__ __launch_bounds__(256) void trans_k(const float* __restrict__ v,
                                               const float* __restrict__ k,
                                               const float* __restrict__ q,
                                               float* __restrict__ vT,
                                               float* __restrict__ kT,
                                               float* __restrict__ qT) {
    __shared__ float tl[32][33];
    int bid = blockIdx.x, tid = threadIdx.x;
    const float* in; float* outp; int tile;
    if (bid < 960)       { int idx = bid >> 5; tile = bid & 31; in = v + (size_t)idx * 32768; outp = vT + (size_t)idx * 32768; }
    else if (bid < 1024) { int i = bid - 960;  int idx = i >> 5; tile = i & 31; in = k + (size_t)idx * 32768; outp = kT + (size_t)idx * 32768; }
    else                 { int i = bid - 1024; int idx = i >> 5; tile = i & 31; in = q + (size_t)idx * 32768; outp = qT + (size_t)idx * 32768; }
    int g0 = (tile >> 2) * 32, w0 = (tile & 3) * 32;
    int tx = tid & 31, ty = tid >> 5;
#pragma unroll
    for (int r = 0; r < 4; ++r)
        tl[ty + 8 * r][tx] = in[(size_t)(g0 + ty + 8 * r) * 128 + w0 + tx];
    __syncthreads();
#pragma unroll
    for (int r = 0; r < 4; ++r)
        outp[(size_t)(w0 + ty + 8 * r) * 256 + g0 + tx] = tl[tx][ty + 8 * r];
}

// ---------- attention 3: H-part MFMA, all 256 g per block. grid = b*128 (b,w) ----------
__global__ __launch_bounds__(256) void attnH_k(const float* __restrict__ qT,
    const float* __restrict__ kT, const float* __restrict__ vT,
    float* __restrict__ outHT, float* __restrict__ m2T, float* __restrict__ S2T) {
    __shared__ char Pl[256 * 128];
    __shared__ char Vl[16 * 128];
    __shared__ float klds[256];
    __shared__ float ol[256][17];
    __shared__ float kabs_s;
    int bid = blockIdx.x;
    int b = bid >> 7, w = bid & 127;
    int tid = threadIdx.x;
    if (tid < 64) {
        f32x4 kk = *(const f32x4*)(kT + ((size_t)b * 128 + w) * 256 + 4 * tid);
        *(f32x4*)&klds[4 * tid] = kk;
        float ka = fmaxf(fmaxf(fabsf(kk.x), fabsf(kk.y)), fmaxf(fabsf(kk.z), fabsf(kk.w)));
#pragma unroll
        for (int off = 32; off >= 1; off >>= 1) ka = fmaxf(ka, __shfl_xor(ka, off));
        if (tid == 0) kabs_s = ka;
    }
    float qs = qT[((size_t)b * 128 + w) * 256 + tid];
    __syncthreads();
    float m2 = fabsf(qs) * kabs_s;
    int ln = tid & 63, wv = tid >> 6;
    f32x4 acc[4];
#pragma unroll
    for (int mt = 0; mt < 4; ++mt) acc[mt] = (f32x4){0.f, 0.f, 0.f, 0.f};
    int swp = (tid & 7) << 4;
    for (int gc = 0; gc < 4; ++gc) {
        int gbase0 = gc * 64;
        {
            int c = tid >> 4, seg = tid & 15;
            int gg = gbase0 + seg * 4;
            u16x4 o;
            if (c < 15) {
                f32x4 vv4 = *(const f32x4*)(vT + (((size_t)b * 15 + c) * 128 + w) * 256 + gg);
                o[0] = f2bf(vv4.x); o[1] = f2bf(vv4.y); o[2] = f2bf(vv4.z); o[3] = f2bf(vv4.w);
            } else {
                o[0] = 0x3F80; o[1] = 0x3F80; o[2] = 0x3F80; o[3] = 0x3F80;
            }
            *(u16x4*)(Vl + ((c * 128 + seg * 8) ^ ((c & 7) << 4))) = o;
        }
#pragma unroll
        for (int g8 = 0; g8 < 64; g8 += 8) {
            f32x4 k0 = *(const f32x4*)&klds[gbase0 + g8];
            f32x4 k1 = *(const f32x4*)&klds[gbase0 + g8 + 4];
            int gbase = gbase0 + g8;
            U8 u;
            float p0 = __expf(fmaf(qs, k0.x, -m2)); if (gbase + 0 == tid) p0 = 0.f;
            float p1 = __expf(fmaf(qs, k0.y, -m2)); if (gbase + 1 == tid) p1 = 0.f;
            float p2 = __expf(fmaf(qs, k0.z, -m2)); if (gbase + 2 == tid) p2 = 0.f;
            float p3 = __expf(fmaf(qs, k0.w, -m2)); if (gbase + 3 == tid) p3 = 0.f;
            float p4 = __expf(fmaf(qs, k1.x, -m2)); if (gbase + 4 == tid) p4 = 0.f;
            float p5 = __expf(fmaf(qs, k1.y, -m2)); if (gbase + 5 == tid) p5 = 0.f;
            float p6 = __expf(fmaf(qs, k1.z, -m2)); if (gbase + 6 == tid) p6 = 0.f;
            float p7 = __expf(fmaf(qs, k1.w, -m2)); if (gbase + 7 == tid) p7 = 0.f;
            u.h[0] = f2bf(p0); u.h[1] = f2bf(p1); u.h[2] = f2bf(p2); u.h[3] = f2bf(p3);
            u.h[4] = f2bf(p4); u.h[5] = f2bf(p5); u.h[6] = f2bf(p6); u.h[7] = f2bf(p7);
            *(bf16x8*)(Pl + tid * 128 + ((g8 * 2) ^ swp)) = u.v;
        }
        __syncthreads();
#pragma unroll
        for (int ks = 0; ks < 2; ++ks) {
            int k2 = (ks * 32 + (ln >> 4) * 8) * 2;
            int n = ln & 15;
            bf16x8 bf = *(const bf16x8*)(Vl + n * 128 + (k2 ^ ((n & 7) << 4)));
#pragma unroll
            for (int mt = 0; mt < 4; ++mt) {
                int row = wv * 64 + mt * 16 + (ln & 15);
                bf16x8 a = *(const bf16x8*)(Pl + row * 128 + (k2 ^ ((row & 7) << 4)));
                acc[mt] = __builtin_amdgcn_mfma_f32_16x16x32_bf16(a, bf, acc[mt], 0, 0, 0);
            }
        }
        __syncthreads();
    }
    {
        int c = ln & 15;
#pragma unroll
        for (int mt = 0; mt < 4; ++mt)
#pragma unroll
            for (int r = 0; r < 4; ++r)
                ol[wv * 64 + mt * 16 + (ln >> 4) * 4 + r][c] = acc[mt][r];
    }
    __syncthreads();
    size_t base = ((size_t)b * 128 + w) * 256 + tid;
    m2T[base] = m2;
    S2T[base] = ol[tid][15];
#pragma unroll
    for (int c = 0; c < 15; ++c)
        outHT[(((size_t)b * 15 + c) * 128 + w) * 256 + tid] = ol[tid][c];
}

// ---------- attention 4: combine W + H + residual ----------
__global__ __launch_bounds__(256) void combine_k(const float* __restrict__ hin,
    const float* __restrict__ accW,
    const float* __restrict__ outHT,
    const float* __restrict__ m1, const float* __restrict__ S1,
    const float* __restrict__ m2T, const float* __restrict__ S2T,
    const float* __restrict__ gptr, float* __restrict__ hout) {
    __shared__ float ot[32][33];
    __shared__ float m2l[32][33], s2l[32][33];
    int bid = blockIdx.x;
    int c = bid % 15, wt = (bid / 15) & 3, ht = (bid / 60) & 7, b = bid / 480;
    int h0 = ht * 32, w0 = wt * 32;
    int tid = threadIdx.x, tx = tid & 31, ty = tid >> 5;
#pragma unroll
    for (int r = 0; r < 4; ++r) {
        int wl = ty + 8 * r;
        size_t tb = ((size_t)b * 128 + w0 + wl) * 256 + h0 + tx;
        size_t ob = (((size_t)b * 15 + c) * 128 + w0 + wl) * 256 + h0 + tx;
        m2l[wl][tx] = m2T[tb];
        s2l[wl][tx] = S2T[tb];
        ot[wl][tx] = outHT[ob];
    }
    __syncthreads();
    float g = gptr[0];
#pragma unroll
    for (int r = 0; r < 4; ++r) {
        int hl = ty + 8 * r;
        int h = h0 + hl, w = w0 + tx;
        size_t hw = ((size_t)b * 256 + h) * 128 + w;
        float m1v = m1[hw], S1v = S1[hw];
        float m2v = m2l[tx][hl], S2v = s2l[tx][hl];
        float mm = fmaxf(m1v, m2v);
        float e1 = __expf(m1v - mm), e2 = __expf(m2v - mm);
        float sc = g / (S1v * e1 + S2v * e2);
        size_t oi = (((size_t)b * 15 + c) * 256 + h) * 128 + w;
        hout[oi] = hin[oi] + sc * e1 * accW[oi] + sc * e2 * ot[tx][hl];
    }
}

extern "C" void kernel_launch(void* const* d_in, const int* in_sizes, int n_in,
                              void* d_out, int out_size, void* d_ws, size_t ws_size,
                              hipStream_t stream) {
    const float* x    = (const float*)d_in[0];
    const float* Wemb = (const float*)d_in[1];
    const float* bemb = (const float*)d_in[2];
    const float* Wq   = (const float*)d_in[3];
    const float* bq   = (const float*)d_in[4];
    const float* Wk   = (const float*)d_in[5];
    const float* bk   = (const float*)d_in[6];
    const float* Wv   = (const float*)d_in[7];
    const float* bv   = (const float*)d_in[8];
    const float* gam  = (const float*)d_in[9];
    const float* Wmlp = (const float*)d_in[10];
    const float* Wp1  = (const float*)d_in[11];
    const float* bp1  = (const float*)d_in[12];
    const float* Wp2  = (const float*)d_in[13];
    const float* bp2  = (const float*)d_in[14];

    float* out = (float*)d_out;
    float* xe  = out + XE_OFF;
    float* xh  = out + XH_OFF;
    float* xp  = out + XP_OFF;
    float* xhp = out + XHP_OFF;

    float* scr    = xhp;
    float* cosb   = scr + SCR_COS;
    float* sinb   = scr + SCR_SIN;
    float* qb     = scr + SCR_Q;
    float* kb     = scr + SCR_K;
    float* vb     = scr + SCR_V;
    float* ha     = scr + SCR_HA;
    float* hb     = scr + SCR_HB;
    float* m1g    = scr + SCR_M1;
    float* S1g    = scr + SCR_S1;
    float* accW   = scr + SCR_AW;
    float* vTb    = scr + SCR_VT;
    float* kTb    = scr + SCR_KT;
    float* qTb    = scr + SCR_QT;
    float* outHT  = scr + SCR_OHT;
    float* m2T    = scr + SCR_M2;
    float* S2T    = scr + SCR_S2;
    u16*   prt    = (u16*)(scr + SCR_PART);
    u16* Wp2t  = (u16*)d_ws;
    u16* Wembt = (u16*)((char*)d_ws + 1048576);
    u16* Wp1t  = (u16*)((char*)d_ws + 2097152);
    u16* Wmlpt = (u16*)((char*)d_ws + 2129920);

    prep_k<<<1088, 256, 0, stream>>>(Wemb, Wp1, Wmlp, Wp2, cosb, sinb,
                                     Wembt, Wp1t, Wmlpt, Wp2t);
    embed_mfma_k<<<dim3(8, 120), 256, 0, stream>>>(x, Wembt, prt);
    embed_reduce_k<<<480, 256, 0, stream>>>(prt, bemb, xe);

    const float* hin = xe;
    float* houts[3] = {ha, hb, ha};
    for (int i = 0; i < 3; ++i) {
        qkvW_k<<<512, 256, 0, stream>>>(hin, Wq + i * 15, bq + i, Wk + i * 15, bk + i,
                                        Wv + i * 225, bv + i * 15, cosb, sinb,
                                        qb, kb, vb, m1g, S1g, accW);
        trans_k<<<1088, 256, 0, stream>>>(vb, kb, qb, vTb, kTb, qTb);
        attnH_k<<<256, 256, 0, stream>>>(qTb, kTb, vTb, outHT, m2T, S2T);
        combine_k<<<1536, 256, 0, stream>>>(hin, accW, outHT, m1g, S1g,
                                            m2T, S2T, gam + i, houts[i]);
        hin = houts[i];
    }

    gemm_bt_k<0, 0, 0><<<dim3(1, 120), 256, 0, stream>>>(hin, Wmlpt, nullptr, xh, 128);
    recover2_k<<<dim3(8, 240), 256, 0, stream>>>(xe, xh, Wp1t, bp1, Wp2t, bp2, xp, xhp);
}

// Round 28
// 205.663 us; speedup vs baseline: 1.0102x; 1.0102x over previous
//
#include <hip/hip_runtime.h>
#include <math.h>

typedef __attribute__((ext_vector_type(8))) short bf16x8;
typedef __attribute__((ext_vector_type(8))) unsigned short u16x8;
typedef __attribute__((ext_vector_type(4))) unsigned short u16x4;
typedef __attribute__((ext_vector_type(4))) float f32x4;
typedef unsigned short u16;

// Shapes: b=2, T=15, Hn=256, D=128, P=64, PPP=4096, REC=3
// d_out layout (f32): x_e[983040] | x_h[983040] | x_p[31457280] | x_h_p[31457280]
#define XE_OFF   0
#define XH_OFF   983040
#define XP_OFF   1966080
#define XHP_OFF  33423360

// scratch (float offsets) inside x_h_p region — all dead before recover(xh->xhp)
#define SCR_COS   0         // 8192
#define SCR_SIN   8192      // 8192
#define SCR_Q     16384     // 65536  q[b][h][w]
#define SCR_K     81920     // 65536  k[b][g][w]
#define SCR_V     147456    // 983040 v[b][c][g][w]
#define SCR_HA    1130496   // 983040
#define SCR_HB    2113536   // 983040
#define SCR_M1    3096576   // 65536  m1[b][h][w]
#define SCR_S1    3162112   // 65536  S1[b][h][w]
#define SCR_AW    3227648   // 983040 accW[b][c][h][w]
#define SCR_VT    4210688   // 983040 vT[b][c][w][g]
#define SCR_KT    5193728   // 65536  kT[b][w][g]
#define SCR_QT    5259264   // 65536  qT[b][w][h]
#define SCR_OHT   5324800   // 983040 outHT0[b][c][w][h]
#define SCR_M2    6307840   // 65536  m2T[b][w][h]
#define SCR_S2    6373376   // 65536  S2T0[b][w][h]
#define SCR_OHT1  6438912   // 983040 outHT1
#define SCR_S21   7421952   // 65536  S2T1
#define SCR_PART  7487488   // 8 x 983040 u16 = 3932160 floats (ends 11419648 < 31457280)
// d_ws layout (bytes): Wp2t[0,1048576) Wembt[1048576,2097152)
//                      Wp1t[2097152,2129920) Wmlpt[2129920,2162688)

__device__ __forceinline__ u16 f2bf(float f) {
    unsigned u = __float_as_uint(f);
    return (u16)((u + 0x7fffu + ((u >> 16) & 1)) >> 16);
}
__device__ __forceinline__ float bf2f(u16 h) {
    return __uint_as_float(((unsigned)h) << 16);
}

union U8 { u16 h[8]; bf16x8 v; u16x8 u; };

// ---------- prep: rope tables + all 4 weight transpose/cvt in ONE launch ----------
__global__ __launch_bounds__(256) void prep_k(const float* __restrict__ Wemb,
                                              const float* __restrict__ Wp1,
                                              const float* __restrict__ Wmlp,
                                              const float* __restrict__ Wp2,
                                              float* __restrict__ cosb, float* __restrict__ sinb,
                                              u16* __restrict__ Wembt, u16* __restrict__ Wp1t,
                                              u16* __restrict__ Wmlpt, u16* __restrict__ Wp2t) {
    __shared__ float tl[32][33];
    int bid = blockIdx.x, tid = threadIdx.x;
    if (bid < 32) {
        int i = bid * 256 + tid;
        int n = i >> 5, j = i & 31;
        float inv = expf(-(float)j * 0.28782313662425573f);  // 10000^(-2j/64)
        float ang = (float)n * inv;
        cosb[i] = cosf(ang);
        sinb[i] = sinf(ang);
        return;
    }
    const float* in; u16* outp; int K, N, gx, gy;
    if (bid < 544)      { int i = bid - 32;  in = Wemb; outp = Wembt; K = 4096; N = 128;  gx = i & 3;   gy = i >> 2; }
    else if (bid < 560) { int i = bid - 544; in = Wp1;  outp = Wp1t;  K = 128;  N = 128;  gx = i & 3;   gy = i >> 2; }
    else if (bid < 576) { int i = bid - 560; in = Wmlp; outp = Wmlpt; K = 128;  N = 128;  gx = i & 3;   gy = i >> 2; }
    else                { int i = bid - 576; in = Wp2;  outp = Wp2t;  K = 128;  N = 4096; gx = i & 127; gy = i >> 7; }
    int n0 = gx * 32, k0 = gy * 32;
    int tx = tid & 31, ty = tid >> 5;
#pragma unroll
    for (int r = 0; r < 4; ++r)
        tl[ty + r * 8][tx] = in[(size_t)(k0 + ty + r * 8) * N + n0 + tx];
    __syncthreads();
#pragma unroll
    for (int r = 0; r < 4; ++r)
        outp[(size_t)(n0 + ty + r * 8) * K + k0 + tx] = f2bf(tl[tx][ty + r * 8]);
}

// ---------- embed: MFMA bf16, split-K x8, coalesced A staging + depth-2 prefetch ----------
// partials stored as bf16 (halves partial round-trip traffic)
__global__ __launch_bounds__(256) void embed_mfma_k(const float* __restrict__ x,
                                                    const u16* __restrict__ Wembt,
                                                    u16* __restrict__ part) {
    __shared__ char Al[64 * 128];
    __shared__ char Bl[128 * 128];
    int ck = blockIdx.x, mt = blockIdx.y;
    int m0 = mt * 64;
    int bt = m0 >> 8;
    int n0r = m0 & 255;
    const float* xb = x + (size_t)bt * 1048576;
    int tid = threadIdx.x;
    int ln = tid & 63, wv = tid >> 6;
    int wm = wv >> 1, wn = wv & 1;

    f32x4 acc[2][4];
#pragma unroll
    for (int mi = 0; mi < 2; ++mi)
#pragma unroll
        for (int ni = 0; ni < 4; ++ni) acc[mi][ni] = (f32x4){0.f, 0.f, 0.f, 0.f};

    // coalesced A staging: wave wv covers n-group (n0r>>4)+wv; lane ln covers
    // floats ln*16..ln*16+15 of the 1024-float (group,py) line.
    int ar = wv * 16 + (ln >> 2);
    int aseg = ln & 3;
    const float* abase = xb + ((size_t)((n0r >> 4) + wv)) * 65536 + ln * 16;
    // B staging coords: 4 chunks per thread
    int bn[4], bk0[4];
#pragma unroll
    for (int j = 0; j < 4; ++j) {
        int c = tid + 256 * j;
        bn[j] = c >> 3; bk0[j] = (c & 7) * 8;
    }

    // depth-2 prefetch buffers: preload phases 0 and 1
    f32x4 af[2][4];
    U8 bfr[2][4];
#pragma unroll
    for (int p = 0; p < 2; ++p) {
        const float* src = abase + (size_t)(ck * 8 + p) * 1024;
#pragma unroll
        for (int j = 0; j < 4; ++j) af[p][j] = ((const f32x4*)src)[j];
        int kb = ck * 512 + p * 64;
#pragma unroll
        for (int j = 0; j < 4; ++j)
            bfr[p][j].u = *(const u16x8*)(Wembt + (size_t)bn[j] * 4096 + kb + bk0[j]);
    }

#pragma unroll
    for (int bk = 0; bk < 8; ++bk) {
        const int cur = bk & 1;           // compile-time after full unroll
        __syncthreads();   // prior MFMA LDS reads complete
        {
            U8 u0, u1;
            u0.h[0] = f2bf(af[cur][0].x); u0.h[1] = f2bf(af[cur][0].y); u0.h[2] = f2bf(af[cur][0].z); u0.h[3] = f2bf(af[cur][0].w);
            u0.h[4] = f2bf(af[cur][1].x); u0.h[5] = f2bf(af[cur][1].y); u0.h[6] = f2bf(af[cur][1].z); u0.h[7] = f2bf(af[cur][1].w);
            u1.h[0] = f2bf(af[cur][2].x); u1.h[1] = f2bf(af[cur][2].y); u1.h[2] = f2bf(af[cur][2].z); u1.h[3] = f2bf(af[cur][2].w);
            u1.h[4] = f2bf(af[cur][3].x); u1.h[5] = f2bf(af[cur][3].y); u1.h[6] = f2bf(af[cur][3].z); u1.h[7] = f2bf(af[cur][3].w);
            int sw = (ar & 7) << 4;
            *(bf16x8*)(Al + ar * 128 + ((aseg * 32) ^ sw))      = u0.v;
            *(bf16x8*)(Al + ar * 128 + ((aseg * 32 + 16) ^ sw)) = u1.v;
#pragma unroll
            for (int j = 0; j < 4; ++j)
                *(bf16x8*)(Bl + bn[j] * 128 + ((bk0[j] * 2) ^ ((bn[j] & 7) << 4))) = bfr[cur][j].v;
        }
        __syncthreads();   // staging visible
        if (bk < 6) {      // prefetch phase bk+2 into the just-freed buffer
            const float* src = abase + (size_t)(ck * 8 + bk + 2) * 1024;
#pragma unroll
            for (int j = 0; j < 4; ++j) af[cur][j] = ((const f32x4*)src)[j];
            int kb = ck * 512 + (bk + 2) * 64;
#pragma unroll
            for (int j = 0; j < 4; ++j)
                bfr[cur][j].u = *(const u16x8*)(Wembt + (size_t)bn[j] * 4096 + kb + bk0[j]);
        }
#pragma unroll
        for (int ks = 0; ks < 2; ++ks) {
            int k2 = (ks * 32 + (ln >> 4) * 8) * 2;
            bf16x8 a[2], b[4];
#pragma unroll
            for (int mi = 0; mi < 2; ++mi) {
                int row = wm * 32 + mi * 16 + (ln & 15);
                a[mi] = *(const bf16x8*)(Al + row * 128 + (k2 ^ ((row & 7) << 4)));
            }
#pragma unroll
            for (int ni = 0; ni < 4; ++ni) {
                int n = wn * 64 + ni * 16 + (ln & 15);
                b[ni] = *(const bf16x8*)(Bl + n * 128 + (k2 ^ ((n & 7) << 4)));
            }
#pragma unroll
            for (int mi = 0; mi < 2; ++mi)
#pragma unroll
                for (int ni = 0; ni < 4; ++ni)
                    acc[mi][ni] = __builtin_amdgcn_mfma_f32_16x16x32_bf16(a[mi], b[ni], acc[mi][ni], 0, 0, 0);
        }
    }
    u16* p = part + (size_t)ck * 983040;
#pragma unroll
    for (int mi = 0; mi < 2; ++mi)
#pragma unroll
        for (int ni = 0; ni < 4; ++ni)
#pragma unroll
            for (int r = 0; r < 4; ++r) {
                int row = m0 + wm * 32 + mi * 16 + (ln >> 4) * 4 + r;
                int col = wn * 64 + ni * 16 + (ln & 15);
                p[(size_t)row * 128 + col] = f2bf(acc[mi][ni][r]);
            }
}

// xe = sum of 8 bf16 partials + bias. grid 480; 8 floats/thread.
__global__ __launch_bounds__(256) void embed_reduce_k(const u16* __restrict__ part,
                                                      const float* __restrict__ bemb,
                                                      float* __restrict__ xe) {
    int i = blockIdx.x * 256 + threadIdx.x;    // 122880 total, 8 floats each
    float s[8];
#pragma unroll
    for (int e = 0; e < 8; ++e) s[e] = 0.f;
#pragma unroll
    for (int j = 0; j < 8; ++j) {
        U8 h; h.u = *(const u16x8*)(part + (size_t)j * 983040 + (size_t)i * 8);
#pragma unroll
        for (int e = 0; e < 8; ++e) s[e] += bf2f(h.h[e]);
    }
    int col0 = (i & 15) * 8;
#pragma unroll
    for (int e = 0; e < 8; ++e) s[e] += bemb[col0 + e];
    float4 o0 = {s[0], s[1], s[2], s[3]};
    float4 o1 = {s[4], s[5], s[6], s[7]};
    ((float4*)(xe + (size_t)i * 8))[0] = o0;
    ((float4*)(xe + (size_t)i * 8))[1] = o1;
}

// ---------- generic K=128 MFMA GEMM (used only for xh = h @ Wmlp) ----------
template<int ABF, int OBF, int HASB>
__global__ __launch_bounds__(256) void gemm_bt_k(const void* __restrict__ Ap,
                                                 const u16* __restrict__ Bt,
                                                 const float* __restrict__ bias,
                                                 void* __restrict__ outp, int N) {
    __shared__ char Al[64 * 256];
    __shared__ char Bl[128 * 256];
    int n0 = blockIdx.x * 128, m0 = blockIdx.y * 64;
    int tid = threadIdx.x;
    int ln = tid & 63, wv = tid >> 6;
    int wm = wv >> 1, wn = wv & 1;
    {
        int row = tid >> 2, kseg = (tid & 3) * 32;
        int sw = (row & 7) << 4;
        if (ABF) {
            const u16* src = (const u16*)Ap + (size_t)(m0 + row) * 128 + kseg;
#pragma unroll
            for (int j = 0; j < 4; ++j) {
                U8 u; u.u = *(const u16x8*)(src + j * 8);
                *(bf16x8*)(Al + row * 256 + (((kseg + j * 8) * 2) ^ sw)) = u.v;
            }
        } else {
            const float* src = (const float*)Ap + (size_t)(m0 + row) * 128 + kseg;
#pragma unroll
            for (int j = 0; j < 4; ++j) {
                float4 f0 = ((const float4*)src)[2 * j];
                float4 f1 = ((const float4*)src)[2 * j + 1];
                U8 u;
                u.h[0] = f2bf(f0.x); u.h[1] = f2bf(f0.y); u.h[2] = f2bf(f0.z); u.h[3] = f2bf(f0.w);
                u.h[4] = f2bf(f1.x); u.h[5] = f2bf(f1.y); u.h[6] = f2bf(f1.z); u.h[7] = f2bf(f1.w);
                *(bf16x8*)(Al + row * 256 + (((kseg + j * 8) * 2) ^ sw)) = u.v;
            }
        }
    }
    {
        int n = tid >> 1, kseg = (tid & 1) * 64;
        int sw = (n & 7) << 4;
        const u16* src = Bt + (size_t)(n0 + n) * 128 + kseg;
#pragma unroll
        for (int j = 0; j < 8; ++j) {
            U8 u; u.u = *(const u16x8*)(src + j * 8);
            *(bf16x8*)(Bl + n * 256 + (((kseg + j * 8) * 2) ^ sw)) = u.v;
        }
    }
    __syncthreads();
    f32x4 acc[2][4];
#pragma unroll
    for (int mi = 0; mi < 2; ++mi)
#pragma unroll
        for (int ni = 0; ni < 4; ++ni) acc[mi][ni] = (f32x4){0.f, 0.f, 0.f, 0.f};
#pragma unroll
    for (int ks = 0; ks < 4; ++ks) {
        int k2 = (ks * 32 + (ln >> 4) * 8) * 2;
        bf16x8 a[2], b[4];
#pragma unroll
        for (int mi = 0; mi < 2; ++mi) {
            int row = wm * 32 + mi * 16 + (ln & 15);
            a[mi] = *(const bf16x8*)(Al + row * 256 + (k2 ^ ((row & 7) << 4)));
        }
#pragma unroll
        for (int ni = 0; ni < 4; ++ni) {
            int n = wn * 64 + ni * 16 + (ln & 15);
            b[ni] = *(const bf16x8*)(Bl + n * 256 + (k2 ^ ((n & 7) << 4)));
        }
#pragma unroll
        for (int mi = 0; mi < 2; ++mi)
#pragma unroll
            for (int ni = 0; ni < 4; ++ni)
                acc[mi][ni] = __builtin_amdgcn_mfma_f32_16x16x32_bf16(a[mi], b[ni], acc[mi][ni], 0, 0, 0);
    }
#pragma unroll
    for (int mi = 0; mi < 2; ++mi)
#pragma unroll
        for (int ni = 0; ni < 4; ++ni)
#pragma unroll
            for (int r = 0; r < 4; ++r) {
                int row = m0 + wm * 32 + mi * 16 + (ln >> 4) * 4 + r;
                int col = n0 + wn * 64 + ni * 16 + (ln & 15);
                float v = acc[mi][ni][r];
                if (HASB) v += bias[col];
                if (OBF) ((u16*)outp)[(size_t)row * N + col] = f2bf(v);
                else     ((float*)outp)[(size_t)row * N + col] = v;
            }
}

// ---------- fused recover x2: both xe->xp and xh->xhp in ONE launch ----------
// grid (8, 240): blockIdx.y < 120 -> xe->xp, else xh->xhp.
__global__ __launch_bounds__(256) void recover2_k(const float* __restrict__ A0,
                                                  const float* __restrict__ A1,
                                                  const u16* __restrict__ Wp1t,
                                                  const float* __restrict__ bp1,
                                                  const u16* __restrict__ Wp2t,
                                                  const float* __restrict__ bp2,
                                                  float* __restrict__ out0,
                                                  float* __restrict__ out1) {
    __shared__ char Zl[64 * 256];    // z bf16
    __shared__ char Bl[64 * 256];    // weight chunk: 64 n-rows x 128 k bf16
    __shared__ char Al2[64 * 256];   // A bf16
    __shared__ float Ol[64][65];     // output chunk staging (dedicated)
    int sel = blockIdx.y >= 120;
    const float* A = sel ? A1 : A0;
    float* outp = sel ? out1 : out0;
    int cb = blockIdx.x * 512, m0 = (blockIdx.y - (sel ? 120 : 0)) * 64;
    int tid = threadIdx.x, ln = tid & 63, wv = tid >> 6;
    int wm = wv >> 1, wn = wv & 1;

    // stage A (f32 -> bf16) into Al2
    {
        int row = tid >> 2, kseg = (tid & 3) * 32;
        int sw = (row & 7) << 4;
        const float* src = A + (size_t)(m0 + row) * 128 + kseg;
#pragma unroll
        for (int j = 0; j < 4; ++j) {
            float4 f0 = ((const float4*)src)[2 * j];
            float4 f1 = ((const float4*)src)[2 * j + 1];
            U8 u;
            u.h[0] = f2bf(f0.x); u.h[1] = f2bf(f0.y); u.h[2] = f2bf(f0.z); u.h[3] = f2bf(f0.w);
            u.h[4] = f2bf(f1.x); u.h[5] = f2bf(f1.y); u.h[6] = f2bf(f1.z); u.h[7] = f2bf(f1.w);
            *(bf16x8*)(Al2 + row * 256 + (((kseg + j * 8) * 2) ^ sw)) = u.v;
        }
    }
    // phase 1: z = A @ Wp1 (+bp1) in 2 chunks of 64 cols
    f32x4 zacc[2][4];
#pragma unroll
    for (int mi = 0; mi < 2; ++mi)
#pragma unroll
        for (int ni = 0; ni < 4; ++ni) zacc[mi][ni] = (f32x4){0.f, 0.f, 0.f, 0.f};
    for (int nc = 0; nc < 2; ++nc) {
        __syncthreads();
        {
            int n = tid >> 2, ks2 = (tid & 3) * 32;
            int swb = (n & 7) << 4;
            const u16* bsrc = Wp1t + (size_t)(nc * 64 + n) * 128 + ks2;
#pragma unroll
            for (int j = 0; j < 4; ++j) {
                U8 u; u.u = *(const u16x8*)(bsrc + j * 8);
                *(bf16x8*)(Bl + n * 256 + (((ks2 + j * 8) * 2) ^ swb)) = u.v;
            }
        }
        __syncthreads();
#pragma unroll
        for (int ks = 0; ks < 4; ++ks) {
            int k2 = (ks * 32 + (ln >> 4) * 8) * 2;
            bf16x8 a[2], b[2];
#pragma unroll
            for (int mi = 0; mi < 2; ++mi) {
                int row = wm * 32 + mi * 16 + (ln & 15);
                a[mi] = *(const bf16x8*)(Al2 + row * 256 + (k2 ^ ((row & 7) << 4)));
            }
#pragma unroll
            for (int ni = 0; ni < 2; ++ni) {
                int n = wn * 32 + ni * 16 + (ln & 15);
                b[ni] = *(const bf16x8*)(Bl + n * 256 + (k2 ^ ((n & 7) << 4)));
            }
#pragma unroll
            for (int mi = 0; mi < 2; ++mi)
#pragma unroll
                for (int ni = 0; ni < 2; ++ni)
                    zacc[mi][nc * 2 + ni] = __builtin_amdgcn_mfma_f32_16x16x32_bf16(a[mi], b[ni], zacc[mi][nc * 2 + ni], 0, 0, 0);
        }
    }
    // write z (bf16) into Zl; visible before first phase-2 read via nb-loop barrier
#pragma unroll
    for (int ni4 = 0; ni4 < 4; ++ni4) {
        int col = (ni4 >> 1) * 64 + wn * 32 + (ni4 & 1) * 16 + (ln & 15);
        float bb = bp1[col];
#pragma unroll
        for (int mi = 0; mi < 2; ++mi)
#pragma unroll
            for (int r = 0; r < 4; ++r) {
                int row = wm * 32 + mi * 16 + (ln >> 4) * 4 + r;
                *(u16*)(Zl + row * 256 + ((col * 2) ^ ((row & 7) << 4))) =
                    f2bf(zacc[mi][ni4][r] + bb);
            }
    }
    // phase 2: out slice in 8 chunks of 64 cols; coalesced write via Ol
    for (int nb = 0; nb < 8; ++nb) {
        __syncthreads();   // z/Ol reads of prev iteration done; Bl reads done
        {
            int n = tid >> 2, ks2 = (tid & 3) * 32;
            int swb = (n & 7) << 4;
            const u16* bsrc = Wp2t + (size_t)(cb + nb * 64 + n) * 128 + ks2;
#pragma unroll
            for (int j = 0; j < 4; ++j) {
                U8 u; u.u = *(const u16x8*)(bsrc + j * 8);
                *(bf16x8*)(Bl + n * 256 + (((ks2 + j * 8) * 2) ^ swb)) = u.v;
            }
        }
        __syncthreads();
        f32x4 acc[2][2];
#pragma unroll
        for (int mi = 0; mi < 2; ++mi)
#pragma unroll
            for (int ni = 0; ni < 2; ++ni) acc[mi][ni] = (f32x4){0.f, 0.f, 0.f, 0.f};
#pragma unroll
        for (int ks = 0; ks < 4; ++ks) {
            int k2 = (ks * 32 + (ln >> 4) * 8) * 2;
            bf16x8 a[2], b[2];
#pragma unroll
            for (int mi = 0; mi < 2; ++mi) {
                int row = wm * 32 + mi * 16 + (ln & 15);
                a[mi] = *(const bf16x8*)(Zl + row * 256 + (k2 ^ ((row & 7) << 4)));
            }
#pragma unroll
            for (int ni = 0; ni < 2; ++ni) {
                int n = wn * 32 + ni * 16 + (ln & 15);
                b[ni] = *(const bf16x8*)(Bl + n * 256 + (k2 ^ ((n & 7) << 4)));
            }
#pragma unroll
            for (int mi = 0; mi < 2; ++mi)
#pragma unroll
                for (int ni = 0; ni < 2; ++ni)
                    acc[mi][ni] = __builtin_amdgcn_mfma_f32_16x16x32_bf16(a[mi], b[ni], acc[mi][ni], 0, 0, 0);
        }
        // stage fragments into Ol [row][col] (bias added here)
#pragma unroll
        for (int ni = 0; ni < 2; ++ni) {
            int coll = wn * 32 + ni * 16 + (ln & 15);
            float bb = bp2[cb + nb * 64 + coll];
#pragma unroll
            for (int mi = 0; mi < 2; ++mi)
#pragma unroll
                for (int r = 0; r < 4; ++r) {
                    int rowl = wm * 32 + mi * 16 + (ln >> 4) * 4 + r;
                    Ol[rowl][coll] = acc[mi][ni][r] + bb;
                }
        }
        __syncthreads();   // Ol visible
        // coalesced write: 16 threads per row -> 256B contiguous per row
#pragma unroll
        for (int j = 0; j < 4; ++j) {
            int e = tid + 256 * j;           // 1024 float4s
            int rowl = e >> 4, c4 = e & 15;
            float4 o;
            o.x = Ol[rowl][c4 * 4 + 0];
            o.y = Ol[rowl][c4 * 4 + 1];
            o.z = Ol[rowl][c4 * 4 + 2];
            o.w = Ol[rowl][c4 * 4 + 3];
            float* dst = outp + (size_t)(m0 + rowl) * 4096 + cb + nb * 64 + c4 * 4;
            __builtin_nontemporal_store(o.x, dst + 0);
            __builtin_nontemporal_store(o.y, dst + 1);
            __builtin_nontemporal_store(o.z, dst + 2);
            __builtin_nontemporal_store(o.w, dst + 3);
        }
    }
}

// ---------- attention 1: qkv + W-part, 256 threads (2 halves), coalesced I/O ----------
__global__ __launch_bounds__(256) void qkvW_k(const float* __restrict__ hin,
    const float* __restrict__ Wq, const float* __restrict__ bq,
    const float* __restrict__ Wk, const float* __restrict__ bk,
    const float* __restrict__ Wv, const float* __restrict__ bv,
    const float* __restrict__ cosb, const float* __restrict__ sinb,
    float* __restrict__ q, float* __restrict__ k, float* __restrict__ v,
    float* __restrict__ m1g, float* __restrict__ S1g, float* __restrict__ accW) {
    __shared__ char Pl[128 * 256];
    __shared__ char Vt[16 * 256];
    __shared__ float klds[128];
    __shared__ float qlds[128];
    __shared__ float red[2];
    __shared__ float ol[128][17];
    int b = blockIdx.x >> 8, hh = blockIdx.x & 255;
    int tid = threadIdx.x;
    int d = tid & 127, half = tid >> 7;

    if (half == 0) {
        float hv[15];
#pragma unroll
        for (int t = 0; t < 15; ++t)
            hv[t] = hin[(((size_t)b * 15 + t) * 256 + hh) * 128 + d];
        float qp = bq[0], kp = bk[0];
#pragma unroll
        for (int t = 0; t < 15; ++t) {
            qp = fmaf(hv[t], Wq[t], qp);
            kp = fmaf(hv[t], Wk[t], kp);
        }
        float qpart = __shfl_xor(qp, 1);
        float kpart = __shfl_xor(kp, 1);
        float qo = qp, ko = kp;
        if (d < 64) {
            int j = d >> 1;
            float c = cosb[hh * 32 + j], s = sinb[hh * 32 + j];
            if (d & 1) { qo = fmaf(qp, c,  qpart * s); ko = fmaf(kp, c,  kpart * s); }
            else       { qo = fmaf(qp, c, -qpart * s); ko = fmaf(kp, c, -kpart * s); }
        }
        q[((size_t)b * 256 + hh) * 128 + d] = qo;
        k[((size_t)b * 256 + hh) * 128 + d] = ko;
        klds[d] = ko;
        qlds[d] = qo;
        float ka = fabsf(ko);
#pragma unroll
        for (int off = 32; off >= 1; off >>= 1) ka = fmaxf(ka, __shfl_xor(ka, off));
        if ((tid & 63) == 0) red[tid >> 6] = ka;
    } else {
        float hv[15];
#pragma unroll
        for (int t = 0; t < 15; ++t)
            hv[t] = hin[(((size_t)b * 15 + t) * 256 + hh) * 128 + d];
        float vv[15];
#pragma unroll
        for (int c = 0; c < 15; ++c) {
            float a = bv[c];
#pragma unroll
            for (int t = 0; t < 15; ++t) a = fmaf(hv[t], Wv[c * 15 + t], a);
            vv[c] = a;
        }
#pragma unroll
        for (int c = 0; c < 15; ++c)
            v[(((size_t)b * 15 + c) * 256 + hh) * 128 + d] = vv[c];
#pragma unroll
        for (int c = 0; c < 15; ++c)
            *(u16*)(Vt + ((c * 256 + d * 2) ^ ((c & 7) << 4))) = f2bf(vv[c]);
        *(u16*)(Vt + ((15 * 256 + d * 2) ^ 112)) = 0x3F80;
    }
    __syncthreads();
    float ka = fmaxf(red[0], red[1]);
    float qo = qlds[d];
    float m1 = fabsf(qo) * ka;
    if (half == 0) m1g[((size_t)b * 256 + hh) * 128 + d] = m1;
    int swp = (d & 7) << 4;
    int u0 = half * 64;
#pragma unroll 4
    for (int u8 = 0; u8 < 64; u8 += 8) {
        f32x4 k0 = *(const f32x4*)&klds[u0 + u8];
        f32x4 k1 = *(const f32x4*)&klds[u0 + u8 + 4];
        U8 u;
        u.h[0] = f2bf(__expf(fmaf(qo, k0.x, -m1)));
        u.h[1] = f2bf(__expf(fmaf(qo, k0.y, -m1)));
        u.h[2] = f2bf(__expf(fmaf(qo, k0.z, -m1)));
        u.h[3] = f2bf(__expf(fmaf(qo, k0.w, -m1)));
        u.h[4] = f2bf(__expf(fmaf(qo, k1.x, -m1)));
        u.h[5] = f2bf(__expf(fmaf(qo, k1.y, -m1)));
        u.h[6] = f2bf(__expf(fmaf(qo, k1.z, -m1)));
        u.h[7] = f2bf(__expf(fmaf(qo, k1.w, -m1)));
        *(bf16x8*)(Pl + d * 256 + (((u0 + u8) * 2) ^ swp)) = u.v;
    }
    __syncthreads();
    int ln = tid & 63, wvv = tid >> 6;
    f32x4 acc[2];
    acc[0] = (f32x4){0.f, 0.f, 0.f, 0.f};
    acc[1] = (f32x4){0.f, 0.f, 0.f, 0.f};
#pragma unroll
    for (int ks = 0; ks < 4; ++ks) {
        int k2 = (ks * 32 + (ln >> 4) * 8) * 2;
        int n = ln & 15;
        bf16x8 bf = *(const bf16x8*)(Vt + n * 256 + (k2 ^ ((n & 7) << 4)));
#pragma unroll
        for (int mt = 0; mt < 2; ++mt) {
            int row = wvv * 32 + mt * 16 + (ln & 15);
            bf16x8 a = *(const bf16x8*)(Pl + row * 256 + (k2 ^ ((row & 7) << 4)));
            acc[mt] = __builtin_amdgcn_mfma_f32_16x16x32_bf16(a, bf, acc[mt], 0, 0, 0);
        }
    }
    {
        int c = ln & 15;
#pragma unroll
        for (int mt = 0; mt < 2; ++mt)
#pragma unroll
            for (int r = 0; r < 4; ++r)
                ol[wvv * 32 + mt * 16 + (ln >> 4) * 4 + r][c] = acc[mt][r];
    }
    __syncthreads();
    if (half == 0) S1g[((size_t)b * 256 + hh) * 128 + d] = ol[d][15];
    for (int e = tid; e < 1920; e += 256) {
        int c = e >> 7, w = e & 127;
        accW[(((size_t)b * 15 + c) * 256 + hh) * 128 + w] = ol[w][c];
    }
}

// ---------- attention 2: tiled transposes v->vT, k->kT, q->qT ----------
__global__ __launch_bounds__(256) void trans_k(const float* __restrict__ v,
                                               const float* __restrict__ k,
                                               const float* __restrict__ q,
                                               float* __restrict__ vT,
                                               float* __restrict__ kT,
                                               float* __restrict__ qT) {
    __shared__ float tl[32][33];
    int bid = blockIdx.x, tid = threadIdx.x;
    const float* in; float* outp; int tile;
    if (bid < 960)       { int idx = bid >> 5; tile = bid & 31; in = v + (size_t)idx * 32768; outp = vT + (size_t)idx * 32768; }
    else if (bid < 1024) { int i = bid - 960;  int idx = i >> 5; tile = i & 31; in = k + (size_t)idx * 32768; outp = kT + (size_t)idx * 32768; }
    else                 { int i = bid - 1024; int idx = i >> 5; tile = i & 31; in = q + (size_t)idx * 32768; outp = qT + (size_t)idx * 32768; }
    int g0 = (tile >> 2) * 32, w0 = (tile & 3) * 32;
    int tx = tid & 31, ty = tid >> 5;
#pragma unroll
    for (int r = 0; r < 4; ++r)
        tl[ty + 8 * r][tx] = in[(size_t)(g0 + ty + 8 * r) * 128 + w0 + tx];
    __syncthreads();
#pragma unroll
    for (int r = 0; r < 4; ++r)
        outp[(size_t)(w0 + ty + 8 * r) * 256 + g0 + tx] = tl[tx][ty + 8 * r];
}

// ---------- attention 3: H-part MFMA, split-g x2. grid = b*128*2 (b,w,ghalf) ----------
__global__ __launch_bounds__(256) void attnH_k(const float* __restrict__ qT,
    const float* __restrict__ kT, const float* __restrict__ vT,
    float* __restrict__ outHT0, float* __restrict__ outHT1,
    float* __restrict__ m2T, float* __restrict__ S2T0, float* __restrict__ S2T1) {
    __shared__ char Pl[256 * 128];
    __shared__ char Vl[16 * 128];
    __shared__ float klds[256];
    __shared__ float ol[256][17];
    __shared__ float kabs_s;
    int bid = blockIdx.x;
    int b = bid >> 8, rem = bid & 255;
    int w = rem >> 1, gh = rem & 1;
    int tid = threadIdx.x;
    if (tid < 64) {
        f32x4 kk = *(const f32x4*)(kT + ((size_t)b * 128 + w) * 256 + 4 * tid);
        *(f32x4*)&klds[4 * tid] = kk;
        float ka = fmaxf(fmaxf(fabsf(kk.x), fabsf(kk.y)), fmaxf(fabsf(kk.z), fabsf(kk.w)));
#pragma unroll
        for (int off = 32; off >= 1; off >>= 1) ka = fmaxf(ka, __shfl_xor(ka, off));
        if (tid == 0) kabs_s = ka;
    }
    float qs = qT[((size_t)b * 128 + w) * 256 + tid];
    __syncthreads();
    float m2 = fabsf(qs) * kabs_s;
    int ln = tid & 63, wv = tid >> 6;
    f32x4 acc[4];
#pragma unroll
    for (int mt = 0; mt < 4; ++mt) acc[mt] = (f32x4){0.f, 0.f, 0.f, 0.f};
    int swp = (tid & 7) << 4;
    for (int gc = 0; gc < 2; ++gc) {
        int gbase0 = gh * 128 + gc * 64;
        {
            int c = tid >> 4, seg = tid & 15;
            int gg = gbase0 + seg * 4;
            u16x4 o;
            if (c < 15) {
                f32x4 vv4 = *(const f32x4*)(vT + (((size_t)b * 15 + c) * 128 + w) * 256 + gg);
                o[0] = f2bf(vv4.x); o[1] = f2bf(vv4.y); o[2] = f2bf(vv4.z); o[3] = f2bf(vv4.w);
            } else {
                o[0] = 0x3F80; o[1] = 0x3F80; o[2] = 0x3F80; o[3] = 0x3F80;
            }
            *(u16x4*)(Vl + ((c * 128 + seg * 8) ^ ((c & 7) << 4))) = o;
        }
#pragma unroll
        for (int g8 = 0; g8 < 64; g8 += 8) {
            f32x4 k0 = *(const f32x4*)&klds[gbase0 + g8];
            f32x4 k1 = *(const f32x4*)&klds[gbase0 + g8 + 4];
            int gbase = gbase0 + g8;
            U8 u;
            float p0 = __expf(fmaf(qs, k0.x, -m2)); if (gbase + 0 == tid) p0 = 0.f;
            float p1 = __expf(fmaf(qs, k0.y, -m2)); if (gbase + 1 == tid) p1 = 0.f;
            float p2 = __expf(fmaf(qs, k0.z, -m2)); if (gbase + 2 == tid) p2 = 0.f;
            float p3 = __expf(fmaf(qs, k0.w, -m2)); if (gbase + 3 == tid) p3 = 0.f;
            float p4 = __expf(fmaf(qs, k1.x, -m2)); if (gbase + 4 == tid) p4 = 0.f;
            float p5 = __expf(fmaf(qs, k1.y, -m2)); if (gbase + 5 == tid) p5 = 0.f;
            float p6 = __expf(fmaf(qs, k1.z, -m2)); if (gbase + 6 == tid) p6 = 0.f;
            float p7 = __expf(fmaf(qs, k1.w, -m2)); if (gbase + 7 == tid) p7 = 0.f;
            u.h[0] = f2bf(p0); u.h[1] = f2bf(p1); u.h[2] = f2bf(p2); u.h[3] = f2bf(p3);
            u.h[4] = f2bf(p4); u.h[5] = f2bf(p5); u.h[6] = f2bf(p6); u.h[7] = f2bf(p7);
            *(bf16x8*)(Pl + tid * 128 + ((g8 * 2) ^ swp)) = u.v;
        }
        __syncthreads();
#pragma unroll
        for (int ks = 0; ks < 2; ++ks) {
            int k2 = (ks * 32 + (ln >> 4) * 8) * 2;
            int n = ln & 15;
            bf16x8 bf = *(const bf16x8*)(Vl + n * 128 + (k2 ^ ((n & 7) << 4)));
#pragma unroll
            for (int mt = 0; mt < 4; ++mt) {
                int row = wv * 64 + mt * 16 + (ln & 15);
                bf16x8 a = *(const bf16x8*)(Pl + row * 128 + (k2 ^ ((row & 7) << 4)));
                acc[mt] = __builtin_amdgcn_mfma_f32_16x16x32_bf16(a, bf, acc[mt], 0, 0, 0);
            }
        }
        __syncthreads();
    }
    {
        int c = ln & 15;
#pragma unroll
        for (int mt = 0; mt < 4; ++mt)
#pragma unroll
            for (int r = 0; r < 4; ++r)
                ol[wv * 64 + mt * 16 + (ln >> 4) * 4 + r][c] = acc[mt][r];
    }
    __syncthreads();
    size_t base = ((size_t)b * 128 + w) * 256 + tid;
    if (gh == 0) m2T[base] = m2;
    float* s2 = gh ? S2T1 : S2T0;
    float* oht = gh ? outHT1 : outHT0;
    s2[base] = ol[tid][15];
#pragma unroll
    for (int c = 0; c < 15; ++c)
        oht[(((size_t)b * 15 + c) * 128 + w) * 256 + tid] = ol[tid][c];
}

// ---------- attention 4: combine W + H0 + H1 + residual ----------
__global__ __launch_bounds__(256) void combine_k(const float* __restrict__ hin,
    const float* __restrict__ accW,
    const float* __restrict__ outHT0, const float* __restrict__ outHT1,
    const float* __restrict__ m1, const float* __restrict__ S1,
    const float* __restrict__ m2T,
    const float* __restrict__ S2T0, const float* __restrict__ S2T1,
    const float* __restrict__ gptr, float* __restrict__ hout) {
    __shared__ float ot[32][33];
    __shared__ float m2l[32][33], s2l[32][33];
    int bid = blockIdx.x;
    int c = bid % 15, wt = (bid / 15) & 3, ht = (bid / 60) & 7, b = bid / 480;
    int h0 = ht * 32, w0 = wt * 32;
    int tid = threadIdx.x, tx = tid & 31, ty = tid >> 5;
#pragma unroll
    for (int r = 0; r < 4; ++r) {
        int wl = ty + 8 * r;
        size_t tb = ((size_t)b * 128 + w0 + wl) * 256 + h0 + tx;
        size_t ob = (((size_t)b * 15 + c) * 128 + w0 + wl) * 256 + h0 + tx;
        m2l[wl][tx] = m2T[tb];
        s2l[wl][tx] = S2T0[tb] + S2T1[tb];
        ot[wl][tx] = outHT0[ob] + outHT1[ob];
    }
    __syncthreads();
    float g = gptr[0];
#pragma unroll
    for (int r = 0; r < 4; ++r) {
        int hl = ty + 8 * r;
        int h = h0 + hl, w = w0 + tx;
        size_t hw = ((size_t)b * 256 + h) * 128 + w;
        float m1v = m1[hw], S1v = S1[hw];
        float m2v = m2l[tx][hl], S2v = s2l[tx][hl];
        float mm = fmaxf(m1v, m2v);
        float e1 = __expf(m1v - mm), e2 = __expf(m2v - mm);
        float sc = g / (S1v * e1 + S2v * e2);
        size_t oi = (((size_t)b * 15 + c) * 256 + h) * 128 + w;
        hout[oi] = hin[oi] + sc * e1 * accW[oi] + sc * e2 * ot[tx][hl];
    }
}

extern "C" void kernel_launch(void* const* d_in, const int* in_sizes, int n_in,
                              void* d_out, int out_size, void* d_ws, size_t ws_size,
                              hipStream_t stream) {
    const float* x    = (const float*)d_in[0];
    const float* Wemb = (const float*)d_in[1];
    const float* bemb = (const float*)d_in[2];
    const float* Wq   = (const float*)d_in[3];
    const float* bq   = (const float*)d_in[4];
    const float* Wk   = (const float*)d_in[5];
    const float* bk   = (const float*)d_in[6];
    const float* Wv   = (const float*)d_in[7];
    const float* bv   = (const float*)d_in[8];
    const float* gam  = (const float*)d_in[9];
    const float* Wmlp = (const float*)d_in[10];
    const float* Wp1  = (const float*)d_in[11];
    const float* bp1  = (const float*)d_in[12];
    const float* Wp2  = (const float*)d_in[13];
    const float* bp2  = (const float*)d_in[14];

    float* out = (float*)d_out;
    float* xe  = out + XE_OFF;
    float* xh  = out + XH_OFF;
    float* xp  = out + XP_OFF;
    float* xhp = out + XHP_OFF;

    float* scr    = xhp;
    float* cosb   = scr + SCR_COS;
    float* sinb   = scr + SCR_SIN;
    float* qb     = scr + SCR_Q;
    float* kb     = scr + SCR_K;
    float* vb     = scr + SCR_V;
    float* ha     = scr + SCR_HA;
    float* hb     = scr + SCR_HB;
    float* m1g    = scr + SCR_M1;
    float* S1g    = scr + SCR_S1;
    float* accW   = scr + SCR_AW;
    float* vTb    = scr + SCR_VT;
    float* kTb    = scr + SCR_KT;
    float* qTb    = scr + SCR_QT;
    float* outHT0 = scr + SCR_OHT;
    float* m2T    = scr + SCR_M2;
    float* S2T0   = scr + SCR_S2;
    float* outHT1 = scr + SCR_OHT1;
    float* S2T1   = scr + SCR_S21;
    u16*   prt    = (u16*)(scr + SCR_PART);
    u16* Wp2t  = (u16*)d_ws;
    u16* Wembt = (u16*)((char*)d_ws + 1048576);
    u16* Wp1t  = (u16*)((char*)d_ws + 2097152);
    u16* Wmlpt = (u16*)((char*)d_ws + 2129920);

    prep_k<<<1088, 256, 0, stream>>>(Wemb, Wp1, Wmlp, Wp2, cosb, sinb,
                                     Wembt, Wp1t, Wmlpt, Wp2t);
    embed_mfma_k<<<dim3(8, 120), 256, 0, stream>>>(x, Wembt, prt);
    embed_reduce_k<<<480, 256, 0, stream>>>(prt, bemb, xe);

    const float* hin = xe;
    float* houts[3] = {ha, hb, ha};
    for (int i = 0; i < 3; ++i) {
        qkvW_k<<<512, 256, 0, stream>>>(hin, Wq + i * 15, bq + i, Wk + i * 15, bk + i,
                                        Wv + i * 225, bv + i * 15, cosb, sinb,
                                        qb, kb, vb, m1g, S1g, accW);
        trans_k<<<1088, 256, 0, stream>>>(vb, kb, qb, vTb, kTb, qTb);
        attnH_k<<<512, 256, 0, stream>>>(qTb, kTb, vTb, outHT0, outHT1, m2T, S2T0, S2T1);
        combine_k<<<1536, 256, 0, stream>>>(hin, accW, outHT0, outHT1, m1g, S1g,
                                            m2T, S2T0, S2T1, gam + i, houts[i]);
        hin = houts[i];
    }

    gemm_bt_k<0, 0, 0><<<dim3(1, 120), 256, 0, stream>>>(hin, Wmlpt, nullptr, xh, 128);
    recover2_k<<<dim3(8, 240), 256, 0, stream>>>(xe, xh, Wp1t, bp1, Wp2t, bp2, xp, xhp);
}

// Round 29
// 196.695 us; speedup vs baseline: 1.0563x; 1.0456x over previous
//
#include <hip/hip_runtime.h>
#include <math.h>

typedef __attribute__((ext_vector_type(8))) short bf16x8;
typedef __attribute__((ext_vector_type(8))) unsigned short u16x8;
typedef __attribute__((ext_vector_type(4))) unsigned short u16x4;
typedef __attribute__((ext_vector_type(4))) float f32x4;
typedef unsigned short u16;

// Shapes: b=2, T=15, Hn=256, D=128, P=64, PPP=4096, REC=3
// d_out layout (f32): x_e[983040] | x_h[983040] | x_p[31457280] | x_h_p[31457280]
#define XE_OFF   0
#define XH_OFF   983040
#define XP_OFF   1966080
#define XHP_OFF  33423360

// scratch (float offsets) inside x_h_p region — all dead before recover(xh->xhp)
#define SCR_COS   0         // 8192
#define SCR_SIN   8192      // 8192
#define SCR_Q     16384     // 65536  q[b][h][w]
#define SCR_K     81920     // 65536  k[b][g][w]
#define SCR_V     147456    // 983040 v[b][c][g][w]
#define SCR_HA    1130496   // 983040
#define SCR_HB    2113536   // 983040
#define SCR_M1    3096576   // 65536  m1[b][h][w]
#define SCR_S1    3162112   // 65536  S1[b][h][w]
#define SCR_AW    3227648   // 983040 accW[b][c][h][w]
#define SCR_VT    4210688   // 983040 vT[b][c][w][g]
#define SCR_KT    5193728   // 65536  kT[b][w][g]
#define SCR_QT    5259264   // 65536  qT[b][w][h]
#define SCR_OHT   5324800   // 983040 outHT0[b][c][w][h]
#define SCR_M2    6307840   // 65536  m2T[b][w][h]
#define SCR_S2    6373376   // 65536  S2T0[b][w][h]
#define SCR_OHT1  6438912   // 983040 outHT1
#define SCR_S21   7421952   // 65536  S2T1
#define SCR_PART  7487488   // 8 x 983040 u16 = 3932160 floats (ends 11419648 < 31457280)
// d_ws layout (bytes): Wp2t[0,1048576) Wembt[1048576,2097152)
//                      Wp1t[2097152,2129920) Wmlpt[2129920,2162688)

__device__ __forceinline__ u16 f2bf(float f) {
    unsigned u = __float_as_uint(f);
    return (u16)((u + 0x7fffu + ((u >> 16) & 1)) >> 16);
}
__device__ __forceinline__ float bf2f(u16 h) {
    return __uint_as_float(((unsigned)h) << 16);
}

union U8 { u16 h[8]; bf16x8 v; u16x8 u; };

// ---------- prep: rope tables + all 4 weight transpose/cvt in ONE launch ----------
__global__ __launch_bounds__(256) void prep_k(const float* __restrict__ Wemb,
                                              const float* __restrict__ Wp1,
                                              const float* __restrict__ Wmlp,
                                              const float* __restrict__ Wp2,
                                              float* __restrict__ cosb, float* __restrict__ sinb,
                                              u16* __restrict__ Wembt, u16* __restrict__ Wp1t,
                                              u16* __restrict__ Wmlpt, u16* __restrict__ Wp2t) {
    __shared__ float tl[32][33];
    int bid = blockIdx.x, tid = threadIdx.x;
    if (bid < 32) {
        int i = bid * 256 + tid;
        int n = i >> 5, j = i & 31;
        float inv = expf(-(float)j * 0.28782313662425573f);  // 10000^(-2j/64)
        float ang = (float)n * inv;
        cosb[i] = cosf(ang);
        sinb[i] = sinf(ang);
        return;
    }
    const float* in; u16* outp; int K, N, gx, gy;
    if (bid < 544)      { int i = bid - 32;  in = Wemb; outp = Wembt; K = 4096; N = 128;  gx = i & 3;   gy = i >> 2; }
    else if (bid < 560) { int i = bid - 544; in = Wp1;  outp = Wp1t;  K = 128;  N = 128;  gx = i & 3;   gy = i >> 2; }
    else if (bid < 576) { int i = bid - 560; in = Wmlp; outp = Wmlpt; K = 128;  N = 128;  gx = i & 3;   gy = i >> 2; }
    else                { int i = bid - 576; in = Wp2;  outp = Wp2t;  K = 128;  N = 4096; gx = i & 127; gy = i >> 7; }
    int n0 = gx * 32, k0 = gy * 32;
    int tx = tid & 31, ty = tid >> 5;
#pragma unroll
    for (int r = 0; r < 4; ++r)
        tl[ty + r * 8][tx] = in[(size_t)(k0 + ty + r * 8) * N + n0 + tx];
    __syncthreads();
#pragma unroll
    for (int r = 0; r < 4; ++r)
        outp[(size_t)(n0 + ty + r * 8) * K + k0 + tx] = f2bf(tl[tx][ty + r * 8]);
}

// ---------- embed: MFMA bf16, split-K x8, coalesced A staging + depth-2 prefetch ----------
// partials stored as bf16 (halves partial round-trip traffic)
__global__ __launch_bounds__(256) void embed_mfma_k(const float* __restrict__ x,
                                                    const u16* __restrict__ Wembt,
                                                    u16* __restrict__ part) {
    __shared__ char Al[64 * 128];
    __shared__ char Bl[128 * 128];
    int ck = blockIdx.x, mt = blockIdx.y;
    int m0 = mt * 64;
    int bt = m0 >> 8;
    int n0r = m0 & 255;
    const float* xb = x + (size_t)bt * 1048576;
    int tid = threadIdx.x;
    int ln = tid & 63, wv = tid >> 6;
    int wm = wv >> 1, wn = wv & 1;

    f32x4 acc[2][4];
#pragma unroll
    for (int mi = 0; mi < 2; ++mi)
#pragma unroll
        for (int ni = 0; ni < 4; ++ni) acc[mi][ni] = (f32x4){0.f, 0.f, 0.f, 0.f};

    // coalesced A staging: wave wv covers n-group (n0r>>4)+wv; lane ln covers
    // floats ln*16..ln*16+15 of the 1024-float (group,py) line.
    int ar = wv * 16 + (ln >> 2);
    int aseg = ln & 3;
    const float* abase = xb + ((size_t)((n0r >> 4) + wv)) * 65536 + ln * 16;
    // B staging coords: 4 chunks per thread
    int bn[4], bk0[4];
#pragma unroll
    for (int j = 0; j < 4; ++j) {
        int c = tid + 256 * j;
        bn[j] = c >> 3; bk0[j] = (c & 7) * 8;
    }

    // depth-2 prefetch buffers: preload phases 0 and 1
    f32x4 af[2][4];
    U8 bfr[2][4];
#pragma unroll
    for (int p = 0; p < 2; ++p) {
        const float* src = abase + (size_t)(ck * 8 + p) * 1024;
#pragma unroll
        for (int j = 0; j < 4; ++j) af[p][j] = ((const f32x4*)src)[j];
        int kb = ck * 512 + p * 64;
#pragma unroll
        for (int j = 0; j < 4; ++j)
            bfr[p][j].u = *(const u16x8*)(Wembt + (size_t)bn[j] * 4096 + kb + bk0[j]);
    }

#pragma unroll
    for (int bk = 0; bk < 8; ++bk) {
        const int cur = bk & 1;           // compile-time after full unroll
        __syncthreads();   // prior MFMA LDS reads complete
        {
            U8 u0, u1;
            u0.h[0] = f2bf(af[cur][0].x); u0.h[1] = f2bf(af[cur][0].y); u0.h[2] = f2bf(af[cur][0].z); u0.h[3] = f2bf(af[cur][0].w);
            u0.h[4] = f2bf(af[cur][1].x); u0.h[5] = f2bf(af[cur][1].y); u0.h[6] = f2bf(af[cur][1].z); u0.h[7] = f2bf(af[cur][1].w);
            u1.h[0] = f2bf(af[cur][2].x); u1.h[1] = f2bf(af[cur][2].y); u1.h[2] = f2bf(af[cur][2].z); u1.h[3] = f2bf(af[cur][2].w);
            u1.h[4] = f2bf(af[cur][3].x); u1.h[5] = f2bf(af[cur][3].y); u1.h[6] = f2bf(af[cur][3].z); u1.h[7] = f2bf(af[cur][3].w);
            int sw = (ar & 7) << 4;
            *(bf16x8*)(Al + ar * 128 + ((aseg * 32) ^ sw))      = u0.v;
            *(bf16x8*)(Al + ar * 128 + ((aseg * 32 + 16) ^ sw)) = u1.v;
#pragma unroll
            for (int j = 0; j < 4; ++j)
                *(bf16x8*)(Bl + bn[j] * 128 + ((bk0[j] * 2) ^ ((bn[j] & 7) << 4))) = bfr[cur][j].v;
        }
        __syncthreads();   // staging visible
        if (bk < 6) {      // prefetch phase bk+2 into the just-freed buffer
            const float* src = abase + (size_t)(ck * 8 + bk + 2) * 1024;
#pragma unroll
            for (int j = 0; j < 4; ++j) af[cur][j] = ((const f32x4*)src)[j];
            int kb = ck * 512 + (bk + 2) * 64;
#pragma unroll
            for (int j = 0; j < 4; ++j)
                bfr[cur][j].u = *(const u16x8*)(Wembt + (size_t)bn[j] * 4096 + kb + bk0[j]);
        }
#pragma unroll
        for (int ks = 0; ks < 2; ++ks) {
            int k2 = (ks * 32 + (ln >> 4) * 8) * 2;
            bf16x8 a[2], b[4];
#pragma unroll
            for (int mi = 0; mi < 2; ++mi) {
                int row = wm * 32 + mi * 16 + (ln & 15);
                a[mi] = *(const bf16x8*)(Al + row * 128 + (k2 ^ ((row & 7) << 4)));
            }
#pragma unroll
            for (int ni = 0; ni < 4; ++ni) {
                int n = wn * 64 + ni * 16 + (ln & 15);
                b[ni] = *(const bf16x8*)(Bl + n * 128 + (k2 ^ ((n & 7) << 4)));
            }
#pragma unroll
            for (int mi = 0; mi < 2; ++mi)
#pragma unroll
                for (int ni = 0; ni < 4; ++ni)
                    acc[mi][ni] = __builtin_amdgcn_mfma_f32_16x16x32_bf16(a[mi], b[ni], acc[mi][ni], 0, 0, 0);
        }
    }
    u16* p = part + (size_t)ck * 983040;
#pragma unroll
    for (int mi = 0; mi < 2; ++mi)
#pragma unroll
        for (int ni = 0; ni < 4; ++ni)
#pragma unroll
            for (int r = 0; r < 4; ++r) {
                int row = m0 + wm * 32 + mi * 16 + (ln >> 4) * 4 + r;
                int col = wn * 64 + ni * 16 + (ln & 15);
                p[(size_t)row * 128 + col] = f2bf(acc[mi][ni][r]);
            }
}

// xe = sum of 8 bf16 partials + bias. grid 480; 8 floats/thread.
__global__ __launch_bounds__(256) void embed_reduce_k(const u16* __restrict__ part,
                                                      const float* __restrict__ bemb,
                                                      float* __restrict__ xe) {
    int i = blockIdx.x * 256 + threadIdx.x;    // 122880 total, 8 floats each
    float s[8];
#pragma unroll
    for (int e = 0; e < 8; ++e) s[e] = 0.f;
#pragma unroll
    for (int j = 0; j < 8; ++j) {
        U8 h; h.u = *(const u16x8*)(part + (size_t)j * 983040 + (size_t)i * 8);
#pragma unroll
        for (int e = 0; e < 8; ++e) s[e] += bf2f(h.h[e]);
    }
    int col0 = (i & 15) * 8;
#pragma unroll
    for (int e = 0; e < 8; ++e) s[e] += bemb[col0 + e];
    float4 o0 = {s[0], s[1], s[2], s[3]};
    float4 o1 = {s[4], s[5], s[6], s[7]};
    ((float4*)(xe + (size_t)i * 8))[0] = o0;
    ((float4*)(xe + (size_t)i * 8))[1] = o1;
}

// ---------- generic K=128 MFMA GEMM (used only for xh = h @ Wmlp) ----------
template<int ABF, int OBF, int HASB>
__global__ __launch_bounds__(256) void gemm_bt_k(const void* __restrict__ Ap,
                                                 const u16* __restrict__ Bt,
                                                 const float* __restrict__ bias,
                                                 void* __restrict__ outp, int N) {
    __shared__ char Al[64 * 256];
    __shared__ char Bl[128 * 256];
    int n0 = blockIdx.x * 128, m0 = blockIdx.y * 64;
    int tid = threadIdx.x;
    int ln = tid & 63, wv = tid >> 6;
    int wm = wv >> 1, wn = wv & 1;
    {
        int row = tid >> 2, kseg = (tid & 3) * 32;
        int sw = (row & 7) << 4;
        if (ABF) {
            const u16* src = (const u16*)Ap + (size_t)(m0 + row) * 128 + kseg;
#pragma unroll
            for (int j = 0; j < 4; ++j) {
                U8 u; u.u = *(const u16x8*)(src + j * 8);
                *(bf16x8*)(Al + row * 256 + (((kseg + j * 8) * 2) ^ sw)) = u.v;
            }
        } else {
            const float* src = (const float*)Ap + (size_t)(m0 + row) * 128 + kseg;
#pragma unroll
            for (int j = 0; j < 4; ++j) {
                float4 f0 = ((const float4*)src)[2 * j];
                float4 f1 = ((const float4*)src)[2 * j + 1];
                U8 u;
                u.h[0] = f2bf(f0.x); u.h[1] = f2bf(f0.y); u.h[2] = f2bf(f0.z); u.h[3] = f2bf(f0.w);
                u.h[4] = f2bf(f1.x); u.h[5] = f2bf(f1.y); u.h[6] = f2bf(f1.z); u.h[7] = f2bf(f1.w);
                *(bf16x8*)(Al + row * 256 + (((kseg + j * 8) * 2) ^ sw)) = u.v;
            }
        }
    }
    {
        int n = tid >> 1, kseg = (tid & 1) * 64;
        int sw = (n & 7) << 4;
        const u16* src = Bt + (size_t)(n0 + n) * 128 + kseg;
#pragma unroll
        for (int j = 0; j < 8; ++j) {
            U8 u; u.u = *(const u16x8*)(src + j * 8);
            *(bf16x8*)(Bl + n * 256 + (((kseg + j * 8) * 2) ^ sw)) = u.v;
        }
    }
    __syncthreads();
    f32x4 acc[2][4];
#pragma unroll
    for (int mi = 0; mi < 2; ++mi)
#pragma unroll
        for (int ni = 0; ni < 4; ++ni) acc[mi][ni] = (f32x4){0.f, 0.f, 0.f, 0.f};
#pragma unroll
    for (int ks = 0; ks < 4; ++ks) {
        int k2 = (ks * 32 + (ln >> 4) * 8) * 2;
        bf16x8 a[2], b[4];
#pragma unroll
        for (int mi = 0; mi < 2; ++mi) {
            int row = wm * 32 + mi * 16 + (ln & 15);
            a[mi] = *(const bf16x8*)(Al + row * 256 + (k2 ^ ((row & 7) << 4)));
        }
#pragma unroll
        for (int ni = 0; ni < 4; ++ni) {
            int n = wn * 64 + ni * 16 + (ln & 15);
            b[ni] = *(const bf16x8*)(Bl + n * 256 + (k2 ^ ((n & 7) << 4)));
        }
#pragma unroll
        for (int mi = 0; mi < 2; ++mi)
#pragma unroll
            for (int ni = 0; ni < 4; ++ni)
                acc[mi][ni] = __builtin_amdgcn_mfma_f32_16x16x32_bf16(a[mi], b[ni], acc[mi][ni], 0, 0, 0);
    }
#pragma unroll
    for (int mi = 0; mi < 2; ++mi)
#pragma unroll
        for (int ni = 0; ni < 4; ++ni)
#pragma unroll
            for (int r = 0; r < 4; ++r) {
                int row = m0 + wm * 32 + mi * 16 + (ln >> 4) * 4 + r;
                int col = n0 + wn * 64 + ni * 16 + (ln & 15);
                float v = acc[mi][ni][r];
                if (HASB) v += bias[col];
                if (OBF) ((u16*)outp)[(size_t)row * N + col] = f2bf(v);
                else     ((float*)outp)[(size_t)row * N + col] = v;
            }
}

// ---------- fused recover x2: both xe->xp and xh->xhp in ONE launch ----------
// grid (8, 240): blockIdx.y < 120 -> xe->xp, else xh->xhp.
// Al2 (phase-1 A tile) and Ol (phase-2 output staging) share one LDS buffer:
// Al2 is dead after phase 1; Ol's first write is after the nb=0 barrier which
// already orders it after every wave's last Al2 read. LDS 66->49.4 KB = 3 blk/CU.
__global__ __launch_bounds__(256) void recover2_k(const float* __restrict__ A0,
                                                  const float* __restrict__ A1,
                                                  const u16* __restrict__ Wp1t,
                                                  const float* __restrict__ bp1,
                                                  const u16* __restrict__ Wp2t,
                                                  const float* __restrict__ bp2,
                                                  float* __restrict__ out0,
                                                  float* __restrict__ out1) {
    __shared__ char Zl[64 * 256];      // z bf16
    __shared__ char Bl[64 * 256];      // weight chunk: 64 n-rows x 128 k bf16
    __shared__ char AlOl[64 * 65 * 4]; // union: phase1 A bf16 (16384B) / phase2 Ol f32 (16640B)
    char* Al2 = AlOl;
    float (*Ol)[65] = (float(*)[65])AlOl;
    int sel = blockIdx.y >= 120;
    const float* A = sel ? A1 : A0;
    float* outp = sel ? out1 : out0;
    int cb = blockIdx.x * 512, m0 = (blockIdx.y - (sel ? 120 : 0)) * 64;
    int tid = threadIdx.x, ln = tid & 63, wv = tid >> 6;
    int wm = wv >> 1, wn = wv & 1;

    // stage A (f32 -> bf16) into Al2
    {
        int row = tid >> 2, kseg = (tid & 3) * 32;
        int sw = (row & 7) << 4;
        const float* src = A + (size_t)(m0 + row) * 128 + kseg;
#pragma unroll
        for (int j = 0; j < 4; ++j) {
            float4 f0 = ((const float4*)src)[2 * j];
            float4 f1 = ((const float4*)src)[2 * j + 1];
            U8 u;
            u.h[0] = f2bf(f0.x); u.h[1] = f2bf(f0.y); u.h[2] = f2bf(f0.z); u.h[3] = f2bf(f0.w);
            u.h[4] = f2bf(f1.x); u.h[5] = f2bf(f1.y); u.h[6] = f2bf(f1.z); u.h[7] = f2bf(f1.w);
            *(bf16x8*)(Al2 + row * 256 + (((kseg + j * 8) * 2) ^ sw)) = u.v;
        }
    }
    // phase 1: z = A @ Wp1 (+bp1) in 2 chunks of 64 cols
    f32x4 zacc[2][4];
#pragma unroll
    for (int mi = 0; mi < 2; ++mi)
#pragma unroll
        for (int ni = 0; ni < 4; ++ni) zacc[mi][ni] = (f32x4){0.f, 0.f, 0.f, 0.f};
    for (int nc = 0; nc < 2; ++nc) {
        __syncthreads();
        {
            int n = tid >> 2, ks2 = (tid & 3) * 32;
            int swb = (n & 7) << 4;
            const u16* bsrc = Wp1t + (size_t)(nc * 64 + n) * 128 + ks2;
#pragma unroll
            for (int j = 0; j < 4; ++j) {
                U8 u; u.u = *(const u16x8*)(bsrc + j * 8);
                *(bf16x8*)(Bl + n * 256 + (((ks2 + j * 8) * 2) ^ swb)) = u.v;
            }
        }
        __syncthreads();
#pragma unroll
        for (int ks = 0; ks < 4; ++ks) {
            int k2 = (ks * 32 + (ln >> 4) * 8) * 2;
            bf16x8 a[2], b[2];
#pragma unroll
            for (int mi = 0; mi < 2; ++mi) {
                int row = wm * 32 + mi * 16 + (ln & 15);
                a[mi] = *(const bf16x8*)(Al2 + row * 256 + (k2 ^ ((row & 7) << 4)));
            }
#pragma unroll
            for (int ni = 0; ni < 2; ++ni) {
                int n = wn * 32 + ni * 16 + (ln & 15);
                b[ni] = *(const bf16x8*)(Bl + n * 256 + (k2 ^ ((n & 7) << 4)));
            }
#pragma unroll
            for (int mi = 0; mi < 2; ++mi)
#pragma unroll
                for (int ni = 0; ni < 2; ++ni)
                    zacc[mi][nc * 2 + ni] = __builtin_amdgcn_mfma_f32_16x16x32_bf16(a[mi], b[ni], zacc[mi][nc * 2 + ni], 0, 0, 0);
        }
    }
    // write z (bf16) into Zl; visible before first phase-2 read via nb-loop barrier
#pragma unroll
    for (int ni4 = 0; ni4 < 4; ++ni4) {
        int col = (ni4 >> 1) * 64 + wn * 32 + (ni4 & 1) * 16 + (ln & 15);
        float bb = bp1[col];
#pragma unroll
        for (int mi = 0; mi < 2; ++mi)
#pragma unroll
            for (int r = 0; r < 4; ++r) {
                int row = wm * 32 + mi * 16 + (ln >> 4) * 4 + r;
                *(u16*)(Zl + row * 256 + ((col * 2) ^ ((row & 7) << 4))) =
                    f2bf(zacc[mi][ni4][r] + bb);
            }
    }
    // phase 2: out slice in 8 chunks of 64 cols; coalesced write via Ol
    for (int nb = 0; nb < 8; ++nb) {
        __syncthreads();   // z/Ol reads of prev iteration done; Bl reads done; Al2 reads done (nb=0)
        {
            int n = tid >> 2, ks2 = (tid & 3) * 32;
            int swb = (n & 7) << 4;
            const u16* bsrc = Wp2t + (size_t)(cb + nb * 64 + n) * 128 + ks2;
#pragma unroll
            for (int j = 0; j < 4; ++j) {
                U8 u; u.u = *(const u16x8*)(bsrc + j * 8);
                *(bf16x8*)(Bl + n * 256 + (((ks2 + j * 8) * 2) ^ swb)) = u.v;
            }
        }
        __syncthreads();
        f32x4 acc[2][2];
#pragma unroll
        for (int mi = 0; mi < 2; ++mi)
#pragma unroll
            for (int ni = 0; ni < 2; ++ni) acc[mi][ni] = (f32x4){0.f, 0.f, 0.f, 0.f};
#pragma unroll
        for (int ks = 0; ks < 4; ++ks) {
            int k2 = (ks * 32 + (ln >> 4) * 8) * 2;
            bf16x8 a[2], b[2];
#pragma unroll
            for (int mi = 0; mi < 2; ++mi) {
                int row = wm * 32 + mi * 16 + (ln & 15);
                a[mi] = *(const bf16x8*)(Zl + row * 256 + (k2 ^ ((row & 7) << 4)));
            }
#pragma unroll
            for (int ni = 0; ni < 2; ++ni) {
                int n = wn * 32 + ni * 16 + (ln & 15);
                b[ni] = *(const bf16x8*)(Bl + n * 256 + (k2 ^ ((n & 7) << 4)));
            }
#pragma unroll
            for (int mi = 0; mi < 2; ++mi)
#pragma unroll
                for (int ni = 0; ni < 2; ++ni)
                    acc[mi][ni] = __builtin_amdgcn_mfma_f32_16x16x32_bf16(a[mi], b[ni], acc[mi][ni], 0, 0, 0);
        }
        // stage fragments into Ol [row][col] (bias added here)
#pragma unroll
        for (int ni = 0; ni < 2; ++ni) {
            int coll = wn * 32 + ni * 16 + (ln & 15);
            float bb = bp2[cb + nb * 64 + coll];
#pragma unroll
            for (int mi = 0; mi < 2; ++mi)
#pragma unroll
                for (int r = 0; r < 4; ++r) {
                    int rowl = wm * 32 + mi * 16 + (ln >> 4) * 4 + r;
                    Ol[rowl][coll] = acc[mi][ni][r] + bb;
                }
        }
        __syncthreads();   // Ol visible
        // coalesced write: 16 threads per row -> 256B contiguous per row
#pragma unroll
        for (int j = 0; j < 4; ++j) {
            int e = tid + 256 * j;           // 1024 float4s
            int rowl = e >> 4, c4 = e & 15;
            float4 o;
            o.x = Ol[rowl][c4 * 4 + 0];
            o.y = Ol[rowl][c4 * 4 + 1];
            o.z = Ol[rowl][c4 * 4 + 2];
            o.w = Ol[rowl][c4 * 4 + 3];
            float* dst = outp + (size_t)(m0 + rowl) * 4096 + cb + nb * 64 + c4 * 4;
            __builtin_nontemporal_store(o.x, dst + 0);
            __builtin_nontemporal_store(o.y, dst + 1);
            __builtin_nontemporal_store(o.z, dst + 2);
            __builtin_nontemporal_store(o.w, dst + 3);
        }
    }
}

// ---------- attention 1: qkv + W-part, 256 threads (2 halves), coalesced I/O ----------
__global__ __launch_bounds__(256) void qkvW_k(const float* __restrict__ hin,
    const float* __restrict__ Wq, const float* __restrict__ bq,
    const float* __restrict__ Wk, const float* __restrict__ bk,
    const float* __restrict__ Wv, const float* __restrict__ bv,
    const float* __restrict__ cosb, const float* __restrict__ sinb,
    float* __restrict__ q, float* __restrict__ k, float* __restrict__ v,
    float* __restrict__ m1g, float* __restrict__ S1g, float* __restrict__ accW) {
    __shared__ char Pl[128 * 256];
    __shared__ char Vt[16 * 256];
    __shared__ float klds[128];
    __shared__ float qlds[128];
    __shared__ float red[2];
    __shared__ float ol[128][17];
    int b = blockIdx.x >> 8, hh = blockIdx.x & 255;
    int tid = threadIdx.x;
    int d = tid & 127, half = tid >> 7;

    if (half == 0) {
        float hv[15];
#pragma unroll
        for (int t = 0; t < 15; ++t)
            hv[t] = hin[(((size_t)b * 15 + t) * 256 + hh) * 128 + d];
        float qp = bq[0], kp = bk[0];
#pragma unroll
        for (int t = 0; t < 15; ++t) {
            qp = fmaf(hv[t], Wq[t], qp);
            kp = fmaf(hv[t], Wk[t], kp);
        }
        float qpart = __shfl_xor(qp, 1);
        float kpart = __shfl_xor(kp, 1);
        float qo = qp, ko = kp;
        if (d < 64) {
            int j = d >> 1;
            float c = cosb[hh * 32 + j], s = sinb[hh * 32 + j];
            if (d & 1) { qo = fmaf(qp, c,  qpart * s); ko = fmaf(kp, c,  kpart * s); }
            else       { qo = fmaf(qp, c, -qpart * s); ko = fmaf(kp, c, -kpart * s); }
        }
        q[((size_t)b * 256 + hh) * 128 + d] = qo;
        k[((size_t)b * 256 + hh) * 128 + d] = ko;
        klds[d] = ko;
        qlds[d] = qo;
        float ka = fabsf(ko);
#pragma unroll
        for (int off = 32; off >= 1; off >>= 1) ka = fmaxf(ka, __shfl_xor(ka, off));
        if ((tid & 63) == 0) red[tid >> 6] = ka;
    } else {
        float hv[15];
#pragma unroll
        for (int t = 0; t < 15; ++t)
            hv[t] = hin[(((size_t)b * 15 + t) * 256 + hh) * 128 + d];
        float vv[15];
#pragma unroll
        for (int c = 0; c < 15; ++c) {
            float a = bv[c];
#pragma unroll
            for (int t = 0; t < 15; ++t) a = fmaf(hv[t], Wv[c * 15 + t], a);
            vv[c] = a;
        }
#pragma unroll
        for (int c = 0; c < 15; ++c)
            v[(((size_t)b * 15 + c) * 256 + hh) * 128 + d] = vv[c];
#pragma unroll
        for (int c = 0; c < 15; ++c)
            *(u16*)(Vt + ((c * 256 + d * 2) ^ ((c & 7) << 4))) = f2bf(vv[c]);
        *(u16*)(Vt + ((15 * 256 + d * 2) ^ 112)) = 0x3F80;
    }
    __syncthreads();
    float ka = fmaxf(red[0], red[1]);
    float qo = qlds[d];
    float m1 = fabsf(qo) * ka;
    if (half == 0) m1g[((size_t)b * 256 + hh) * 128 + d] = m1;
    int swp = (d & 7) << 4;
    int u0 = half * 64;
#pragma unroll 4
    for (int u8 = 0; u8 < 64; u8 += 8) {
        f32x4 k0 = *(const f32x4*)&klds[u0 + u8];
        f32x4 k1 = *(const f32x4*)&klds[u0 + u8 + 4];
        U8 u;
        u.h[0] = f2bf(__expf(fmaf(qo, k0.x, -m1)));
        u.h[1] = f2bf(__expf(fmaf(qo, k0.y, -m1)));
        u.h[2] = f2bf(__expf(fmaf(qo, k0.z, -m1)));
        u.h[3] = f2bf(__expf(fmaf(qo, k0.w, -m1)));
        u.h[4] = f2bf(__expf(fmaf(qo, k1.x, -m1)));
        u.h[5] = f2bf(__expf(fmaf(qo, k1.y, -m1)));
        u.h[6] = f2bf(__expf(fmaf(qo, k1.z, -m1)));
        u.h[7] = f2bf(__expf(fmaf(qo, k1.w, -m1)));
        *(bf16x8*)(Pl + d * 256 + (((u0 + u8) * 2) ^ swp)) = u.v;
    }
    __syncthreads();
    int ln = tid & 63, wvv = tid >> 6;
    f32x4 acc[2];
    acc[0] = (f32x4){0.f, 0.f, 0.f, 0.f};
    acc[1] = (f32x4){0.f, 0.f, 0.f, 0.f};
#pragma unroll
    for (int ks = 0; ks < 4; ++ks) {
        int k2 = (ks * 32 + (ln >> 4) * 8) * 2;
        int n = ln & 15;
        bf16x8 bf = *(const bf16x8*)(Vt + n * 256 + (k2 ^ ((n & 7) << 4)));
#pragma unroll
        for (int mt = 0; mt < 2; ++mt) {
            int row = wvv * 32 + mt * 16 + (ln & 15);
            bf16x8 a = *(const bf16x8*)(Pl + row * 256 + (k2 ^ ((row & 7) << 4)));
            acc[mt] = __builtin_amdgcn_mfma_f32_16x16x32_bf16(a, bf, acc[mt], 0, 0, 0);
        }
    }
    {
        int c = ln & 15;
#pragma unroll
        for (int mt = 0; mt < 2; ++mt)
#pragma unroll
            for (int r = 0; r < 4; ++r)
                ol[wvv * 32 + mt * 16 + (ln >> 4) * 4 + r][c] = acc[mt][r];
    }
    __syncthreads();
    if (half == 0) S1g[((size_t)b * 256 + hh) * 128 + d] = ol[d][15];
    for (int e = tid; e < 1920; e += 256) {
        int c = e >> 7, w = e & 127;
        accW[(((size_t)b * 15 + c) * 256 + hh) * 128 + w] = ol[w][c];
    }
}

// ---------- attention 2: tiled transposes v->vT, k->kT, q->qT ----------
__global__ __launch_bounds__(256) void trans_k(const float* __restrict__ v,
                                               const float* __restrict__ k,
                                               const float* __restrict__ q,
                                               float* __restrict__ vT,
                                               float* __restrict__ kT,
                                               float* __restrict__ qT) {
    __shared__ float tl[32][33];
    int bid = blockIdx.x, tid = threadIdx.x;
    const float* in; float* outp; int tile;
    if (bid < 960)       { int idx = bid >> 5; tile = bid & 31; in = v + (size_t)idx * 32768; outp = vT + (size_t)idx * 32768; }
    else if (bid < 1024) { int i = bid - 960;  int idx = i >> 5; tile = i & 31; in = k + (size_t)idx * 32768; outp = kT + (size_t)idx * 32768; }
    else                 { int i = bid - 1024; int idx = i >> 5; tile = i & 31; in = q + (size_t)idx * 32768; outp = qT + (size_t)idx * 32768; }
    int g0 = (tile >> 2) * 32, w0 = (tile & 3) * 32;
    int tx = tid & 31, ty = tid >> 5;
#pragma unroll
    for (int r = 0; r < 4; ++r)
        tl[ty + 8 * r][tx] = in[(size_t)(g0 + ty + 8 * r) * 128 + w0 + tx];
    __syncthreads();
#pragma unroll
    for (int r = 0; r < 4; ++r)
        outp[(size_t)(w0 + ty + 8 * r) * 256 + g0 + tx] = tl[tx][ty + 8 * r];
}

// ---------- attention 3: H-part MFMA, split-g x2. grid = b*128*2 (b,w,ghalf) ----------
__global__ __launch_bounds__(256) void attnH_k(const float* __restrict__ qT,
    const float* __restrict__ kT, const float* __restrict__ vT,
    float* __restrict__ outHT0, float* __restrict__ outHT1,
    float* __restrict__ m2T, float* __restrict__ S2T0, float* __restrict__ S2T1) {
    __shared__ char Pl[256 * 128];
    __shared__ char Vl[16 * 128];
    __shared__ float klds[256];
    __shared__ float ol[256][17];
    __shared__ float kabs_s;
    int bid = blockIdx.x;
    int b = bid >> 8, rem = bid & 255;
    int w = rem >> 1, gh = rem & 1;
    int tid = threadIdx.x;
    if (tid < 64) {
        f32x4 kk = *(const f32x4*)(kT + ((size_t)b * 128 + w) * 256 + 4 * tid);
        *(f32x4*)&klds[4 * tid] = kk;
        float ka = fmaxf(fmaxf(fabsf(kk.x), fabsf(kk.y)), fmaxf(fabsf(kk.z), fabsf(kk.w)));
#pragma unroll
        for (int off = 32; off >= 1; off >>= 1) ka = fmaxf(ka, __shfl_xor(ka, off));
        if (tid == 0) kabs_s = ka;
    }
    float qs = qT[((size_t)b * 128 + w) * 256 + tid];
    __syncthreads();
    float m2 = fabsf(qs) * kabs_s;
    int ln = tid & 63, wv = tid >> 6;
    f32x4 acc[4];
#pragma unroll
    for (int mt = 0; mt < 4; ++mt) acc[mt] = (f32x4){0.f, 0.f, 0.f, 0.f};
    int swp = (tid & 7) << 4;
    for (int gc = 0; gc < 2; ++gc) {
        int gbase0 = gh * 128 + gc * 64;
        {
            int c = tid >> 4, seg = tid & 15;
            int gg = gbase0 + seg * 4;
            u16x4 o;
            if (c < 15) {
                f32x4 vv4 = *(const f32x4*)(vT + (((size_t)b * 15 + c) * 128 + w) * 256 + gg);
                o[0] = f2bf(vv4.x); o[1] = f2bf(vv4.y); o[2] = f2bf(vv4.z); o[3] = f2bf(vv4.w);
            } else {
                o[0] = 0x3F80; o[1] = 0x3F80; o[2] = 0x3F80; o[3] = 0x3F80;
            }
            *(u16x4*)(Vl + ((c * 128 + seg * 8) ^ ((c & 7) << 4))) = o;
        }
#pragma unroll
        for (int g8 = 0; g8 < 64; g8 += 8) {
            f32x4 k0 = *(const f32x4*)&klds[gbase0 + g8];
            f32x4 k1 = *(const f32x4*)&klds[gbase0 + g8 + 4];
            int gbase = gbase0 + g8;
            U8 u;
            float p0 = __expf(fmaf(qs, k0.x, -m2)); if (gbase + 0 == tid) p0 = 0.f;
            float p1 = __expf(fmaf(qs, k0.y, -m2)); if (gbase + 1 == tid) p1 = 0.f;
            float p2 = __expf(fmaf(qs, k0.z, -m2)); if (gbase + 2 == tid) p2 = 0.f;
            float p3 = __expf(fmaf(qs, k0.w, -m2)); if (gbase + 3 == tid) p3 = 0.f;
            float p4 = __expf(fmaf(qs, k1.x, -m2)); if (gbase + 4 == tid) p4 = 0.f;
            float p5 = __expf(fmaf(qs, k1.y, -m2)); if (gbase + 5 == tid) p5 = 0.f;
            float p6 = __expf(fmaf(qs, k1.z, -m2)); if (gbase + 6 == tid) p6 = 0.f;
            float p7 = __expf(fmaf(qs, k1.w, -m2)); if (gbase + 7 == tid) p7 = 0.f;
            u.h[0] = f2bf(p0); u.h[1] = f2bf(p1); u.h[2] = f2bf(p2); u.h[3] = f2bf(p3);
            u.h[4] = f2bf(p4); u.h[5] = f2bf(p5); u.h[6] = f2bf(p6); u.h[7] = f2bf(p7);
            *(bf16x8*)(Pl + tid * 128 + ((g8 * 2) ^ swp)) = u.v;
        }
        __syncthreads();
#pragma unroll
        for (int ks = 0; ks < 2; ++ks) {
            int k2 = (ks * 32 + (ln >> 4) * 8) * 2;
            int n = ln & 15;
            bf16x8 bf = *(const bf16x8*)(Vl + n * 128 + (k2 ^ ((n & 7) << 4)));
#pragma unroll
            for (int mt = 0; mt < 4; ++mt) {
                int row = wv * 64 + mt * 16 + (ln & 15);
                bf16x8 a = *(const bf16x8*)(Pl + row * 128 + (k2 ^ ((row & 7) << 4)));
                acc[mt] = __builtin_amdgcn_mfma_f32_16x16x32_bf16(a, bf, acc[mt], 0, 0, 0);
            }
        }
        __syncthreads();
    }
    {
        int c = ln & 15;
#pragma unroll
        for (int mt = 0; mt < 4; ++mt)
#pragma unroll
            for (int r = 0; r < 4; ++r)
                ol[wv * 64 + mt * 16 + (ln >> 4) * 4 + r][c] = acc[mt][r];
    }
    __syncthreads();
    size_t base = ((size_t)b * 128 + w) * 256 + tid;
    if (gh == 0) m2T[base] = m2;
    float* s2 = gh ? S2T1 : S2T0;
    float* oht = gh ? outHT1 : outHT0;
    s2[base] = ol[tid][15];
#pragma unroll
    for (int c = 0; c < 15; ++c)
        oht[(((size_t)b * 15 + c) * 128 + w) * 256 + tid] = ol[tid][c];
}

// ---------- attention 4: combine W + H0 + H1 + residual ----------
__global__ __launch_bounds__(256) void combine_k(const float* __restrict__ hin,
    const float* __restrict__ accW,
    const float* __restrict__ outHT0, const float* __restrict__ outHT1,
    const float* __restrict__ m1, const float* __restrict__ S1,
    const float* __restrict__ m2T,
    const float* __restrict__ S2T0, const float* __restrict__ S2T1,
    const float* __restrict__ gptr, float* __restrict__ hout) {
    __shared__ float ot[32][33];
    __shared__ float m2l[32][33], s2l[32][33];
    int bid = blockIdx.x;
    int c = bid % 15, wt = (bid / 15) & 3, ht = (bid / 60) & 7, b = bid / 480;
    int h0 = ht * 32, w0 = wt * 32;
    int tid = threadIdx.x, tx = tid & 31, ty = tid >> 5;
#pragma unroll
    for (int r = 0; r < 4; ++r) {
        int wl = ty + 8 * r;
        size_t tb = ((size_t)b * 128 + w0 + wl) * 256 + h0 + tx;
        size_t ob = (((size_t)b * 15 + c) * 128 + w0 + wl) * 256 + h0 + tx;
        m2l[wl][tx] = m2T[tb];
        s2l[wl][tx] = S2T0[tb] + S2T1[tb];
        ot[wl][tx] = outHT0[ob] + outHT1[ob];
    }
    __syncthreads();
    float g = gptr[0];
#pragma unroll
    for (int r = 0; r < 4; ++r) {
        int hl = ty + 8 * r;
        int h = h0 + hl, w = w0 + tx;
        size_t hw = ((size_t)b * 256 + h) * 128 + w;
        float m1v = m1[hw], S1v = S1[hw];
        float m2v = m2l[tx][hl], S2v = s2l[tx][hl];
        float mm = fmaxf(m1v, m2v);
        float e1 = __expf(m1v - mm), e2 = __expf(m2v - mm);
        float sc = g / (S1v * e1 + S2v * e2);
        size_t oi = (((size_t)b * 15 + c) * 256 + h) * 128 + w;
        hout[oi] = hin[oi] + sc * e1 * accW[oi] + sc * e2 * ot[tx][hl];
    }
}

extern "C" void kernel_launch(void* const* d_in, const int* in_sizes, int n_in,
                              void* d_out, int out_size, void* d_ws, size_t ws_size,
                              hipStream_t stream) {
    const float* x    = (const float*)d_in[0];
    const float* Wemb = (const float*)d_in[1];
    const float* bemb = (const float*)d_in[2];
    const float* Wq   = (const float*)d_in[3];
    const float* bq   = (const float*)d_in[4];
    const float* Wk   = (const float*)d_in[5];
    const float* bk   = (const float*)d_in[6];
    const float* Wv   = (const float*)d_in[7];
    const float* bv   = (const float*)d_in[8];
    const float* gam  = (const float*)d_in[9];
    const float* Wmlp = (const float*)d_in[10];
    const float* Wp1  = (const float*)d_in[11];
    const float* bp1  = (const float*)d_in[12];
    const float* Wp2  = (const float*)d_in[13];
    const float* bp2  = (const float*)d_in[14];

    float* out = (float*)d_out;
    float* xe  = out + XE_OFF;
    float* xh  = out + XH_OFF;
    float* xp  = out + XP_OFF;
    float* xhp = out + XHP_OFF;

    float* scr    = xhp;
    float* cosb   = scr + SCR_COS;
    float* sinb   = scr + SCR_SIN;
    float* qb     = scr + SCR_Q;
    float* kb     = scr + SCR_K;
    float* vb     = scr + SCR_V;
    float* ha     = scr + SCR_HA;
    float* hb     = scr + SCR_HB;
    float* m1g    = scr + SCR_M1;
    float* S1g    = scr + SCR_S1;
    float* accW   = scr + SCR_AW;
    float* vTb    = scr + SCR_VT;
    float* kTb    = scr + SCR_KT;
    float* qTb    = scr + SCR_QT;
    float* outHT0 = scr + SCR_OHT;
    float* m2T    = scr + SCR_M2;
    float* S2T0   = scr + SCR_S2;
    float* outHT1 = scr + SCR_OHT1;
    float* S2T1   = scr + SCR_S21;
    u16*   prt    = (u16*)(scr + SCR_PART);
    u16* Wp2t  = (u16*)d_ws;
    u16* Wembt = (u16*)((char*)d_ws + 1048576);
    u16* Wp1t  = (u16*)((char*)d_ws + 2097152);
    u16* Wmlpt = (u16*)((char*)d_ws + 2129920);

    prep_k<<<1088, 256, 0, stream>>>(Wemb, Wp1, Wmlp, Wp2, cosb, sinb,
                                     Wembt, Wp1t, Wmlpt, Wp2t);
    embed_mfma_k<<<dim3(8, 120), 256, 0, stream>>>(x, Wembt, prt);
    embed_reduce_k<<<480, 256, 0, stream>>>(prt, bemb, xe);

    const float* hin = xe;
    float* houts[3] = {ha, hb, ha};
    for (int i = 0; i < 3; ++i) {
        qkvW_k<<<512, 256, 0, stream>>>(hin, Wq + i * 15, bq + i, Wk + i * 15, bk + i,
                                        Wv + i * 225, bv + i * 15, cosb, sinb,
                                        qb, kb, vb, m1g, S1g, accW);
        trans_k<<<1088, 256, 0, stream>>>(vb, kb, qb, vTb, kTb, qTb);
        attnH_k<<<512, 256, 0, stream>>>(qTb, kTb, vTb, outHT0, outHT1, m2T, S2T0, S2T1);
        combine_k<<<1536, 256, 0, stream>>>(hin, accW, outHT0, outHT1, m1g, S1g,
                                            m2T, S2T0, S2T1, gam + i, houts[i]);
        hin = houts[i];
    }

    gemm_bt_k<0, 0, 0><<<dim3(1, 120), 256, 0, stream>>>(hin, Wmlpt, nullptr, xh, 128);
    recover2_k<<<dim3(8, 240), 256, 0, stream>>>(xe, xh, Wp1t, bp1, Wp2t, bp2, xp, xhp);
}